// Round 8
// baseline (607.070 us; speedup 1.0000x reference)
//
#include <hip/hip_runtime.h>
#include <math.h>

// ---- problem constants (fixed by setup_inputs) ----
#define BB   8
#define S    6144
#define SM1  6143          // memory rows; x[:,SM1,:] == x_pre
#define DM   512
#define H    8
#define DK   64
#define M    32
#define WN   6113          // k + T - M + 1
#define DA   256
#define DAh  32
#define DP   128
#define DPh  16
#define EPSN 1e-12f

// ---- workspace layout (float offsets) ----
#define WS_WKT    0                       // H*DM*DK bf16 packed Wk
#define WS_WKAT   262144                  // H*DA*DAh bf16 packed Wka
#define WS_WKPT   327680                  // H*DP*DPh bf16 packed Wkp
#define WS_QHAT   344064                  // B*H*M*DK fp32
#define WS_QAHAT  475136
#define WS_QPHAT  477184
#define WS_LOGITS 478208                  // B*H*WN
#define WS_XBAR   869440                  // B*H*DM
#define WS_ALAST  902208
#define WS_RES    902272
#define WS_GI     902784
#define WS_WQM    950400                  // H*DK*DM masked Wq fp32
#define WS_XBF    1212544                 // B*S*DM bf16 = 12582912 float-slots
#define N_LOGITS  391232
#define N_XBAR    32768

typedef __attribute__((ext_vector_type(8))) short short8;
typedef __attribute__((ext_vector_type(4))) float f32x4;

__device__ inline unsigned short f2bf(float f) {
    union { float f; unsigned u; } v; v.f = f;
    unsigned r = v.u + 0x7fffu + ((v.u >> 16) & 1u);   // RNE
    return (unsigned short)(r >> 16);
}
__device__ inline float bf2f(unsigned short u) {
    union { unsigned u; float f; } v; v.u = ((unsigned)u) << 16; return v.f;
}

union S8U { short8 v; unsigned short e[8]; };

// ===========================================================================
// prelude: prep_weights + gi + qaqp + xcast fused (all independent)
// ===========================================================================
#define PREP_NB  2368
#define GI_NB    248
#define QAQP_NB  64
#define XCAST_NB 12288

__global__ __launch_bounds__(256) void prelude_k(
    const float* __restrict__ Wk, const float* __restrict__ Wka,
    const float* __restrict__ Wkp, const float* __restrict__ Wq,
    const int* __restrict__ G,
    unsigned short* __restrict__ wkb, unsigned short* __restrict__ wkab,
    unsigned short* __restrict__ wkpb, float* __restrict__ wqm,
    const float* __restrict__ memory, const float* __restrict__ x_pre,
    const float* __restrict__ W_ih, const float* __restrict__ b_ih,
    float* __restrict__ gi_all, unsigned short* __restrict__ xbf,
    const float* __restrict__ aux, const float* __restrict__ pos,
    const float* __restrict__ Wqa, const float* __restrict__ bqa,
    const float* __restrict__ Wqp, const float* __restrict__ bqp,
    float* __restrict__ qahat, float* __restrict__ qphat)
{
    int bx = blockIdx.x, tid = threadIdx.x;
    __shared__ float pa[32][8];
    __shared__ float pp[16][16];

    if (bx < PREP_NB) {
        int idx = bx * 256 + tid;
        if (idx < H*DM*DK) {
            int k = idx & 63; int d = (idx >> 6) & 511; int h = idx >> 15;
            float v = Wk[(size_t)(h*DK + k)*DM + d] * (float)G[k*DK + (d & 63)];
            wkb[(size_t)h*DM*DK + (((d >> 3)*DK + k) << 3) + (d & 7)] = f2bf(v);
        }
        int i2 = idx - H*DM*DK;
        if (i2 >= 0 && i2 < H*DA*DAh) {
            int h = i2 >> 13; int r = i2 & 8191;
            int j = r & 7; int f = r >> 3;
            int c = f & 31; int a = (f >> 5)*8 + j;
            wkab[i2] = f2bf(Wka[(size_t)(h*DAh + c)*DA + a]);
        }
        int i3 = idx - H*DM*DK - H*DA*DAh;
        if (i3 >= 0 && i3 < H*DP*DPh) {
            int h = i3 >> 11; int r = i3 & 2047;
            int j = r & 7; int f = r >> 3;
            int c = f & 15; int p = (f >> 4)*8 + j;
            wkpb[i3] = f2bf(Wkp[(size_t)(h*DPh + c)*DP + p]);
        }
        int i4 = idx - H*DM*DK - H*DA*DAh - H*DP*DPh;
        if (i4 >= 0 && i4 < H*DK*DM) {
            int d = i4 & 511; int k = (i4 >> 9) & 63;
            wqm[i4] = Wq[i4] * (float)G[k*DK + (d & 63)];
        }
        return;
    }
    if (bx < PREP_NB + GI_NB) {
        if (tid < 192) {
            int gx = bx - PREP_NB;
            int t = gx >> 3, b = gx & 7, c = tid;
            const float* xr = memory + ((size_t)b*SM1 + (S - M) + t)*DM;
            const float* wr = W_ih + (size_t)c*DM;
            float s = b_ih[c];
            for (int d = 0; d < DM; d += 4) {
                float4 x4 = *(const float4*)(xr + d);
                float4 w4 = *(const float4*)(wr + d);
                s += x4.x*w4.x + x4.y*w4.y + x4.z*w4.z + x4.w*w4.w;
            }
            gi_all[((size_t)t*BB + b)*192 + c] = s;
        }
        return;
    }
    if (bx < PREP_NB + GI_NB + QAQP_NB) {
        int bh = bx - PREP_NB - GI_NB;
        int b = bh >> 3, h = bh & 7;
        {
            int c = tid & 31, ch = tid >> 5;
            const float* ar = aux + ((size_t)b*S + (S-1))*DA + ch*32;
            const float* wv = Wqa + (size_t)(h*DAh + c)*DA + ch*32;
            float s = 0.f;
            #pragma unroll
            for (int a = 0; a < 32; a += 4) {
                float4 a4 = *(const float4*)(ar + a);
                float4 w4 = *(const float4*)(wv + a);
                s += a4.x*w4.x + a4.y*w4.y + a4.z*w4.z + a4.w*w4.w;
            }
            pa[c][ch] = s;
        }
        {
            int c = tid & 15, ch = tid >> 4;
            const float* pr = pos + ((size_t)b*S + (S-1))*DP + ch*8;
            const float* wv = Wqp + (size_t)(h*DPh + c)*DP + ch*8;
            float4 a4 = *(const float4*)(pr);
            float4 w4 = *(const float4*)(wv);
            float4 a5 = *(const float4*)(pr + 4);
            float4 w5 = *(const float4*)(wv + 4);
            pp[c][ch] = a4.x*w4.x + a4.y*w4.y + a4.z*w4.z + a4.w*w4.w
                      + a5.x*w5.x + a5.y*w5.y + a5.z*w5.z + a5.w*w5.w;
        }
        __syncthreads();
        if (tid < 32) {
            float q = bqa[h*DAh + tid];
            #pragma unroll
            for (int ch = 0; ch < 8; ++ch) q += pa[tid][ch];
            float ss = q*q;
            #pragma unroll
            for (int d2 = 1; d2 <= 16; d2 <<= 1) ss += __shfl_xor(ss, d2);
            qahat[(size_t)bh*DAh + tid] = q / fmaxf(sqrtf(ss), EPSN);
        } else if (tid >= 64 && tid < 80) {
            int c = tid - 64;
            float q = bqp[h*DPh + c];
            #pragma unroll
            for (int ch = 0; ch < 16; ++ch) q += pp[c][ch];
            float ss = q*q;
            #pragma unroll
            for (int d2 = 1; d2 <= 8; d2 <<= 1) ss += __shfl_xor(ss, d2);
            qphat[(size_t)bh*DPh + c] = q / fmaxf(sqrtf(ss), EPSN);
        }
        return;
    }
    {   // xcast: x (memory ++ x_pre) fp32 -> bf16 row-major xbf[b][t][d]
        size_t e = ((size_t)(bx - PREP_NB - GI_NB - QAQP_NB)*256 + tid)*8;
        int b = (int)(e / ((size_t)S*DM));
        size_t r = e - (size_t)b*S*DM;
        int t = (int)(r >> 9);
        int d = (int)(r & 511);
        const float* src = (t < SM1) ? memory + ((size_t)b*SM1 + t)*DM + d
                                     : x_pre + (size_t)b*DM + d;
        float4 v0 = *(const float4*)src, v1 = *(const float4*)(src + 4);
        S8U t8;
        t8.e[0]=f2bf(v0.x); t8.e[1]=f2bf(v0.y); t8.e[2]=f2bf(v0.z); t8.e[3]=f2bf(v0.w);
        t8.e[4]=f2bf(v1.x); t8.e[5]=f2bf(v1.y); t8.e[6]=f2bf(v1.z); t8.e[7]=f2bf(v1.w);
        *(short8*)(xbf + e) = t8.v;
    }
}

// ===========================================================================
// qhat (1024 blocks) + gru_scan (2 blocks, 4 batches each) in one launch.
// ===========================================================================
__global__ __launch_bounds__(256) void qhat_gru_k(
    const float* __restrict__ memory, const float* __restrict__ x_pre,
    const float* __restrict__ wqm, const float* __restrict__ bq,
    float* __restrict__ qhat,
    const float* __restrict__ gi_all, const float* __restrict__ W_hh,
    const float* __restrict__ b_hh, float* __restrict__ res)
{
    int bx = blockIdx.x;
    int tid = threadIdx.x;
    __shared__ float part[2][4][64];

    if (bx < 1024) {
        int mp = bx & 15;
        int h  = (bx >> 4) & 7;
        int b  = bx >> 7;
        int k = tid & 63, dq = tid >> 6;

        int m0 = mp*2;
        int t0 = S - M + m0, t1 = t0 + 1;
        const float* x0 = ((t0 < SM1) ? memory + ((size_t)b*SM1 + t0)*DM
                                      : x_pre + (size_t)b*DM) + dq*128;
        const float* x1 = ((t1 < SM1) ? memory + ((size_t)b*SM1 + t1)*DM
                                      : x_pre + (size_t)b*DM) + dq*128;
        const float* wr = wqm + (size_t)(h*DK + k)*DM + dq*128;

        float s0 = 0.f, s1 = 0.f;
        #pragma unroll 8
        for (int d = 0; d < 128; d += 4) {
            float4 w4 = *(const float4*)(wr + d);
            float4 a4 = *(const float4*)(x0 + d);
            float4 b4 = *(const float4*)(x1 + d);
            s0 += w4.x*a4.x + w4.y*a4.y + w4.z*a4.z + w4.w*a4.w;
            s1 += w4.x*b4.x + w4.y*b4.y + w4.z*b4.z + w4.w*b4.w;
        }

        part[0][dq][k] = s0;
        part[1][dq][k] = s1;
        __syncthreads();

        if (tid < 128) {
            int mi = tid >> 6;
            int kk = tid & 63;
            float q = part[mi][0][kk] + part[mi][1][kk] + part[mi][2][kk] + part[mi][3][kk]
                    + bq[h*DK + kk];
            float ss = q*q;
            #pragma unroll
            for (int d2 = 1; d2 <= 32; d2 <<= 1) ss += __shfl_xor(ss, d2);
            qhat[((size_t)(b*H + h)*M + (m0 + mi))*DK + kk] = q / fmaxf(sqrtf(ss), EPSN);
        }
        return;
    }

    // ---- gru part: blocks 1024,1025; wave = one batch (b = bg*4 + wave)
    {
        int bg = bx - 1024;
        int b = bg*4 + (tid >> 6);
        int l = tid & 63;

        float w0[64], w1[64], w2[64];
        {
            const float* r0p = W_hh + (size_t)l*DK;
            const float* r1p = W_hh + (size_t)(64 + l)*DK;
            const float* r2p = W_hh + (size_t)(128 + l)*DK;
            #pragma unroll
            for (int i = 0; i < 16; ++i) {
                float4 a = *(const float4*)(r0p + i*4);
                w0[i*4]=a.x; w0[i*4+1]=a.y; w0[i*4+2]=a.z; w0[i*4+3]=a.w;
                float4 c = *(const float4*)(r1p + i*4);
                w1[i*4]=c.x; w1[i*4+1]=c.y; w1[i*4+2]=c.z; w1[i*4+3]=c.w;
                float4 e = *(const float4*)(r2p + i*4);
                w2[i*4]=e.x; w2[i*4+1]=e.y; w2[i*4+2]=e.z; w2[i*4+3]=e.w;
            }
        }
        float bh0 = b_hh[l], bh1 = b_hh[64 + l], bh2 = b_hh[128 + l];

        float h = 0.f;
        const float* g0 = gi_all + (size_t)b*192;
        float gr = g0[l], gz = g0[64 + l], gn = g0[128 + l];

        #pragma unroll 1
        for (int t = 0; t < 31; ++t) {
            float a0 = bh0, a1 = bh1, a2 = bh2;
            #pragma unroll
            for (int k = 0; k < 64; ++k) {
                float hk = __int_as_float(__builtin_amdgcn_readlane(__float_as_int(h), k));
                a0 += hk * w0[k];
                a1 += hk * w1[k];
                a2 += hk * w2[k];
            }
            float ngr = 0.f, ngz = 0.f, ngn = 0.f;
            if (t < 30) {
                const float* g2 = gi_all + ((size_t)(t+1)*BB + b)*192;
                ngr = g2[l]; ngz = g2[64 + l]; ngn = g2[128 + l];
            }
            float r = 1.f / (1.f + expf(-(gr + a0)));
            float z = 1.f / (1.f + expf(-(gz + a1)));
            float n = tanhf(gn + r * a2);
            h = (1.f - z)*n + z*h;
            gr = ngr; gz = ngz; gn = ngn;
        }
        res[b*DK + l] = h;
    }
}

// ===========================================================================
// proj bodies — LDS arena is now 16640 B (was 33280: ka's full-DA staging
// forced all 12288 fused blocks to 33KB -> 4 blocks/CU -> Occupancy 34%,
// which for this latency-bound kernel doubled runtime vs standalone's 67%.
// ka now stages DA in TWO 128-col passes (16x520 each); kp already 16640;
// kproj needs 14204. 16.6KB -> 8 blocks/CU possible).
// ===========================================================================
#define SMEM_BYTES 16640

// kproj v3 body (round-1 verbatim): A-frags direct from global bf16 xbf,
// B-frags direct from packed wkb. Zero barriers in the K-loop.
__device__ __forceinline__ void kproj3_body(int bxx, int tid, unsigned char* smemraw,
    const unsigned short* __restrict__ xbf, const unsigned short* __restrict__ wkb,
    const float* __restrict__ bk, const float* __restrict__ qhat,
    const float* __restrict__ wscal, float* __restrict__ logits)
{
    int tile = bxx % 96, h = (bxx / 96) & 7, b = bxx / (96*8);
    int t0 = tile * 64;
    int wave = tid >> 6, lane = tid & 63;
    int quad = lane >> 4, l16 = lane & 15;

    typedef unsigned short row72[72];
    row72* Qs = (row72*)smemraw;                       // 32 x 72 shorts = 4608 B
    row72* Kb = (row72*)(smemraw + 32*72*2);           // 64 x 72 shorts = 9216 B
    float* tnloc = (float*)(smemraw + 96*72*2);        // 95 floats = 380 B (tot 14204)

    {   // stage Qs bf16
        const float* qsrc = qhat + (size_t)(b*H + h)*M*DK;
        int i = tid * 8;
        float4 a0 = *(const float4*)(qsrc + i);
        float4 a1 = *(const float4*)(qsrc + i + 4);
        S8U t8;
        t8.e[0]=f2bf(a0.x); t8.e[1]=f2bf(a0.y); t8.e[2]=f2bf(a0.z); t8.e[3]=f2bf(a0.w);
        t8.e[4]=f2bf(a1.x); t8.e[5]=f2bf(a1.y); t8.e[6]=f2bf(a1.z); t8.e[7]=f2bf(a1.w);
        *(short8*)&Qs[i >> 6][i & 63] = t8.v;
    }
    if (tid < 95) tnloc[tid] = 0.f;

    f32x4 acc[4];
    #pragma unroll
    for (int nt = 0; nt < 4; ++nt) acc[nt] = (f32x4){0.f,0.f,0.f,0.f};

    const unsigned short* xrow = xbf + ((size_t)b*S + t0 + wave*16 + l16)*DM;
    const unsigned short* wh = wkb + (size_t)h*DM*DK;

    #pragma unroll
    for (int ch = 0; ch < 4; ++ch) {
        #pragma unroll
        for (int ks = 0; ks < 4; ++ks) {
            short8 a = *(const short8*)(xrow + ch*128 + ks*32 + quad*8);
            #pragma unroll
            for (int nt = 0; nt < 4; ++nt) {
                short8 bf = *(const short8*)(wh + (((ch*16 + ks*4 + quad)*DK) + nt*16 + l16)*8);
                acc[nt] = __builtin_amdgcn_mfma_f32_16x16x32_bf16(a, bf, acc[nt], 0, 0, 0);
            }
        }
    }

    {   // bias + row l2-norm (butterfly over 16-lane quad group) + bf16 Kb
        float vv[4][4];
        float ss[4] = {0.f, 0.f, 0.f, 0.f};
        #pragma unroll
        for (int nt = 0; nt < 4; ++nt) {
            float bkv = bk[h*DK + nt*16 + l16];
            #pragma unroll
            for (int reg = 0; reg < 4; ++reg) {
                float v = acc[nt][reg] + bkv;
                vv[nt][reg] = v;
                ss[reg] += v*v;
            }
        }
        #pragma unroll
        for (int d2 = 1; d2 <= 8; d2 <<= 1)
            #pragma unroll
            for (int reg = 0; reg < 4; ++reg) ss[reg] += __shfl_xor(ss[reg], d2);
        #pragma unroll
        for (int reg = 0; reg < 4; ++reg) {
            float inv = 1.f / fmaxf(sqrtf(ss[reg]), EPSN);
            #pragma unroll
            for (int nt = 0; nt < 4; ++nt)
                Kb[wave*16 + quad*4 + reg][nt*16 + l16] = f2bf(vv[nt][reg] * inv);
        }
    }
    __syncthreads();

    {   // banded Q.K^T: 32 m-rows x 64 t-cols; per-diagonal LDS scatter
        int mtile = wave & 1;
        int thalf = (wave >> 1) * 32;
        f32x4 acc2[2];
        acc2[0] = (f32x4){0.f,0.f,0.f,0.f};
        acc2[1] = (f32x4){0.f,0.f,0.f,0.f};
        #pragma unroll
        for (int ks = 0; ks < 2; ++ks) {
            short8 a = *(const short8*)&Qs[mtile*16 + l16][ks*32 + quad*8];
            #pragma unroll
            for (int nt = 0; nt < 2; ++nt) {
                short8 kf = *(const short8*)&Kb[thalf + nt*16 + l16][ks*32 + quad*8];
                acc2[nt] = __builtin_amdgcn_mfma_f32_16x16x32_bf16(a, kf, acc2[nt], 0, 0, 0);
            }
        }
        int m0 = mtile*16 + quad*4;
        #pragma unroll
        for (int nt = 0; nt < 2; ++nt) {
            int tl = thalf + nt*16 + l16;
            #pragma unroll
            for (int reg = 0; reg < 4; ++reg) {
                int mm = m0 + reg;
                int j = t0 + tl - mm;
                if (j >= 0 && j < WN)
                    atomicAdd(&tnloc[tl - mm + 31], acc2[nt][reg]);
            }
        }
    }
    __syncthreads();
    if (tid < 95) {
        int j = t0 + tid - 31;
        if (j >= 0 && j < WN)
            atomicAdd(&logits[(size_t)(b*H + h)*WN + j], wscal[0]*(1.f/32.f)*tnloc[tid]);
    }
}

// ka body: 2 heads per block, TWO-PASS staging (DA split 128+128) so LDS
// fits 16640 B. Accumulators persist across passes; per head the global ks
// order is still 0..7 -> bit-identical accumulation.
__device__ __forceinline__ void ka_body(int g, int tid, unsigned char* smemraw,
    const float* __restrict__ aux, const unsigned short* __restrict__ wkab,
    const float* __restrict__ bka, const float* __restrict__ qahat,
    const float* __restrict__ wa, float* __restrict__ logits)
{
    int tile = g % 96;
    int hp   = (g / 96) & 3;
    int b    = g / 384;
    int j0   = tile * 64;
    int wave = tid >> 6, lane = tid & 63;
    int quad = lane >> 4, l16 = lane & 15;

    unsigned short* Xa = (unsigned short*)smemraw;     // 16*520 shorts = 16640 B

    int r = tid >> 2, seg = tid & 3;
    int jcl = j0 + r; if (jcl > WN-1) jcl = WN-1;
    int tt = r >> 4, lo = r & 15;
    const float* arb = aux + ((size_t)b*S + (31 + jcl))*DA;

    f32x4 acc[2][2];
    #pragma unroll
    for (int hi = 0; hi < 2; ++hi)
        #pragma unroll
        for (int nt = 0; nt < 2; ++nt) acc[hi][nt] = (f32x4){0.f,0.f,0.f,0.f};

    #pragma unroll
    for (int p = 0; p < 2; ++p) {
        if (p) __syncthreads();                // pass-0 compute done
        {   // stage d in [128p, 128p+128): thread covers 32 floats
            const float* ar = arb + p*128 + seg*32;
            #pragma unroll
            for (int gg = 0; gg < 4; ++gg) {
                float4 v0 = *(const float4*)(ar + gg*8);
                float4 v1 = *(const float4*)(ar + gg*8 + 4);
                S8U t8;
                t8.e[0]=f2bf(v0.x); t8.e[1]=f2bf(v0.y); t8.e[2]=f2bf(v0.z); t8.e[3]=f2bf(v0.w);
                t8.e[4]=f2bf(v1.x); t8.e[5]=f2bf(v1.y); t8.e[6]=f2bf(v1.z); t8.e[7]=f2bf(v1.w);
                // local k-slot = seg, quad-slot = gg  (same mapping as 1-pass)
                *(short8*)&Xa[(tt*4 + seg)*520 + (gg*16 + lo)*8] = t8.v;
            }
        }
        __syncthreads();
        #pragma unroll
        for (int hi = 0; hi < 2; ++hi) {
            int h = hp*2 + hi;
            const unsigned short* wsrc = wkab + (size_t)h*DA*DAh;
            #pragma unroll
            for (int ks = 0; ks < 4; ++ks) {
                short8 a = *(const short8*)&Xa[(wave*4 + ks)*520 + lane*8];
                #pragma unroll
                for (int nt = 0; nt < 2; ++nt) {
                    short8 bf = *(const short8*)(wsrc +
                        (size_t)((((p*4 + ks)*4 + quad)*32) + nt*16 + l16)*8);
                    acc[hi][nt] = __builtin_amdgcn_mfma_f32_16x16x32_bf16(
                        a, bf, acc[hi][nt], 0, 0, 0);
                }
            }
        }
    }

    float wav = wa[0];
    #pragma unroll
    for (int hi = 0; hi < 2; ++hi) {
        int h = hp*2 + hi;
        float bk0 = bka[h*DAh + l16], bk1 = bka[h*DAh + 16 + l16];
        float q0 = qahat[(size_t)(b*H + h)*DAh + l16];
        float q1 = qahat[(size_t)(b*H + h)*DAh + 16 + l16];
        #pragma unroll
        for (int reg = 0; reg < 4; ++reg) {
            float v0 = acc[hi][0][reg] + bk0;
            float v1 = acc[hi][1][reg] + bk1;
            float ss = v0*v0 + v1*v1;
            float dp = v0*q0 + v1*q1;
            #pragma unroll
            for (int d2 = 1; d2 <= 8; d2 <<= 1) {
                ss += __shfl_xor(ss, d2);
                dp += __shfl_xor(dp, d2);
            }
            if (l16 == 0) {
                int j = j0 + wave*16 + quad*4 + reg;
                if (j < WN)
                    atomicAdd(&logits[(size_t)(b*H + h)*WN + j],
                              wav * dp / fmaxf(sqrtf(ss), EPSN));
            }
        }
    }
}

// kp body: 2 heads per block (LDS 16*520 = 16640 B, unchanged).
__device__ __forceinline__ void kp_body(int g, int tid, unsigned char* smemraw,
    const float* __restrict__ pos, const unsigned short* __restrict__ wkpb,
    const float* __restrict__ bkp, const float* __restrict__ qphat,
    const float* __restrict__ wp, float* __restrict__ logits)
{
    int tile = g % 96;
    int hp   = (g / 96) & 3;
    int b    = g / 384;
    int j0   = tile * 64;
    int wave = tid >> 6, lane = tid & 63;
    int quad = lane >> 4, l16 = lane & 15;

    unsigned short* Xp = (unsigned short*)smemraw;     // 16*520 shorts

    {
        int r = tid >> 2, seg = tid & 3;
        int j = j0 + r; if (j > WN-1) j = WN-1;
        const float* pr = pos + ((size_t)b*S + (31 + j))*DP + seg*32;
        int tt = r >> 4, lo = r & 15;
        #pragma unroll
        for (int gg = 0; gg < 4; ++gg) {
            float4 v0 = *(const float4*)(pr + gg*8);
            float4 v1 = *(const float4*)(pr + gg*8 + 4);
            int d0 = seg*32 + gg*8;
            int ks = d0 >> 5, qd = (d0 >> 3) & 3;
            S8U t8;
            t8.e[0]=f2bf(v0.x); t8.e[1]=f2bf(v0.y); t8.e[2]=f2bf(v0.z); t8.e[3]=f2bf(v0.w);
            t8.e[4]=f2bf(v1.x); t8.e[5]=f2bf(v1.y); t8.e[6]=f2bf(v1.z); t8.e[7]=f2bf(v1.w);
            *(short8*)&Xp[(tt*4 + ks)*520 + (qd*16 + lo)*8] = t8.v;
        }
    }
    __syncthreads();

    float wpv = wp[0];
    #pragma unroll
    for (int hi = 0; hi < 2; ++hi) {
        int h = hp*2 + hi;
        const unsigned short* wsrc = wkpb + (size_t)h*DP*DPh;
        f32x4 acc = (f32x4){0.f,0.f,0.f,0.f};
        #pragma unroll
        for (int ks = 0; ks < 4; ++ks) {
            short8 a = *(const short8*)&Xp[(wave*4 + ks)*520 + lane*8];
            short8 bf = *(const short8*)(wsrc + (size_t)(((ks*4 + quad)*16) + l16)*8);
            acc = __builtin_amdgcn_mfma_f32_16x16x32_bf16(a, bf, acc, 0, 0, 0);
        }
        float bk0 = bkp[h*DPh + l16];
        float q0 = qphat[(size_t)(b*H + h)*DPh + l16];
        #pragma unroll
        for (int reg = 0; reg < 4; ++reg) {
            float v = acc[reg] + bk0;
            float ss = v*v;
            float dp = v*q0;
            #pragma unroll
            for (int d2 = 1; d2 <= 8; d2 <<= 1) {
                ss += __shfl_xor(ss, d2);
                dp += __shfl_xor(dp, d2);
            }
            if (l16 == 0) {
                int j = j0 + wave*16 + quad*4 + reg;
                if (j < WN)
                    atomicAdd(&logits[(size_t)(b*H + h)*WN + j],
                              wpv * dp / fmaxf(sqrtf(ss), EPSN));
            }
        }
    }
}

// ---------------------------------------------------------------------------
// fused proj launch: kproj(6144) + ka(3072) + kp(3072), interleaved 2:1:1.
#define KA_NB 3072
__global__ __launch_bounds__(256, 4) void proj_fused_k(
    const unsigned short* __restrict__ xbf, const unsigned short* __restrict__ wkb,
    const float* __restrict__ bk, const float* __restrict__ qhat,
    const float* __restrict__ w,
    const float* __restrict__ aux, const unsigned short* __restrict__ wkab,
    const float* __restrict__ bka, const float* __restrict__ qahat,
    const float* __restrict__ wa,
    const float* __restrict__ pos, const unsigned short* __restrict__ wkpb,
    const float* __restrict__ bkp, const float* __restrict__ qphat,
    const float* __restrict__ wp,
    float* __restrict__ logits)
{
    __shared__ __align__(16) unsigned char smemraw[SMEM_BYTES];
    int bx = blockIdx.x;
    int g = bx >> 2, r = bx & 3;
    int tid = threadIdx.x;
    if (r < 2)
        kproj3_body(g*2 + r, tid, smemraw, xbf, wkb, bk, qhat, w, logits);
    else if (r == 2)
        ka_body(g, tid, smemraw, aux, wkab, bka, qahat, wa, logits);
    else
        kp_body(g, tid, smemraw, pos, wkpb, bkp, qphat, wp, logits);
}

// small-path standalone wrappers
__global__ __launch_bounds__(256, 2) void ka_only_k(
    const float* __restrict__ aux, const unsigned short* __restrict__ wkab,
    const float* __restrict__ bka, const float* __restrict__ qahat,
    const float* __restrict__ wa, float* __restrict__ logits)
{
    __shared__ __align__(16) unsigned char smemraw[SMEM_BYTES];
    ka_body(blockIdx.x, threadIdx.x, smemraw, aux, wkab, bka, qahat, wa, logits);
}
__global__ __launch_bounds__(256, 2) void kp_only_k(
    const float* __restrict__ pos, const unsigned short* __restrict__ wkpb,
    const float* __restrict__ bkp, const float* __restrict__ qphat,
    const float* __restrict__ wp, float* __restrict__ logits)
{
    __shared__ __align__(16) unsigned char smemraw[SMEM_BYTES];
    kp_body(blockIdx.x, threadIdx.x, smemraw, pos, wkpb, bkp, qphat, wp, logits);
}

// ---------------------------------------------------------------------------
// OLD kproj (fallback when workspace too small for xbf)
__global__ __launch_bounds__(256, 2) void kproj_band_mfma2(
    const float* __restrict__ memory, const float* __restrict__ x_pre,
    const unsigned short* __restrict__ wkb, const float* __restrict__ bk,
    const float* __restrict__ qhat, const float* __restrict__ wscal,
    float* __restrict__ logits)
{
    int bx = blockIdx.x;
    int hp = bx & 3, b = (bx >> 2) & 7, tile = bx >> 5;
    int t0 = tile * 128;
    int tid = threadIdx.x;
    int wave = tid >> 6, lane = tid & 63;
    int quad = lane >> 4, l16 = lane & 15;

    __shared__ unsigned short Xf[32*520];
    __shared__ unsigned short Wf[16*520];
    __shared__ unsigned short Kb[128][72];
    __shared__ unsigned short Qs[M][72];
    __shared__ float tnloc[159];

    if (tid < 159) tnloc[tid] = 0.f;
    {
        int h = hp*2;
        const float* qsrc = qhat + (size_t)(b*H + h)*M*DK;
        int i = tid * 8;
        float4 a0 = *(const float4*)(qsrc + i);
        float4 a1 = *(const float4*)(qsrc + i + 4);
        S8U t8;
        t8.e[0]=f2bf(a0.x); t8.e[1]=f2bf(a0.y); t8.e[2]=f2bf(a0.z); t8.e[3]=f2bf(a0.w);
        t8.e[4]=f2bf(a1.x); t8.e[5]=f2bf(a1.y); t8.e[6]=f2bf(a1.z); t8.e[7]=f2bf(a1.w);
        *(short8*)&Qs[i >> 6][i & 63] = t8.v;
    }

    f32x4 acc[2][2][4];
    #pragma unroll
    for (int hi = 0; hi < 2; ++hi)
        #pragma unroll
        for (int mt = 0; mt < 2; ++mt)
            #pragma unroll
            for (int nt = 0; nt < 4; ++nt) acc[hi][mt][nt] = (f32x4){0.f,0.f,0.f,0.f};

    for (int ch = 0; ch < 4; ++ch) {
        __syncthreads();
        {
            int r = tid >> 1, half = tid & 1;
            int t = t0 + r;
            const float* xr = ((t < SM1) ? (memory + ((size_t)b*SM1 + t)*DM)
                                         : (x_pre + (size_t)b*DM)) + ch*128 + half*64;
            int tt = r >> 4, lo = r & 15;
            #pragma unroll
            for (int g = 0; g < 8; ++g) {
                float4 v0 = *(const float4*)(xr + g*8);
                float4 v1 = *(const float4*)(xr + g*8 + 4);
                int d0 = half*64 + g*8;
                int ks = d0 >> 5, qd = (d0 >> 3) & 3;
                S8U t8;
                t8.e[0]=f2bf(v0.x); t8.e[1]=f2bf(v0.y); t8.e[2]=f2bf(v0.z); t8.e[3]=f2bf(v0.w);
                t8.e[4]=f2bf(v1.x); t8.e[5]=f2bf(v1.y); t8.e[6]=f2bf(v1.z); t8.e[7]=f2bf(v1.w);
                *(short8*)&Xf[(tt*4 + ks)*520 + (qd*16 + lo)*8] = t8.v;
            }
        }
        {
            const unsigned short* src = wkb + (size_t)(hp*2)*DM*DK + (size_t)ch*8192;
            #pragma unroll
            for (int i = 0; i < 4; ++i) {
                int f = tid + 256*i;
                *(short8*)&Wf[(f >> 6)*520 + (f & 63)*8] = *(const short8*)(src + f*8);
            }
        }
        __syncthreads();
        #pragma unroll
        for (int ks = 0; ks < 4; ++ks) {
            short8 a0 = *(const short8*)&Xf[((wave*2 + 0)*4 + ks)*520 + lane*8];
            short8 a1 = *(const short8*)&Xf[((wave*2 + 1)*4 + ks)*520 + lane*8];
            #pragma unroll
            for (int nt = 0; nt < 4; ++nt) {
                short8 bf = *(const short8*)&Wf[(ks*4 + quad)*520 + (nt*16 + l16)*8];
                acc[0][0][nt] = __builtin_amdgcn_mfma_f32_16x16x32_bf16(a0, bf, acc[0][0][nt], 0, 0, 0);
                acc[0][1][nt] = __builtin_amdgcn_mfma_f32_16x16x32_bf16(a1, bf, acc[0][1][nt], 0, 0, 0);
            }
        }
        __syncthreads();
        {
            const unsigned short* src = wkb + (size_t)(hp*2 + 1)*DM*DK + (size_t)ch*8192;
            #pragma unroll
            for (int i = 0; i < 4; ++i) {
                int f = tid + 256*i;
                *(short8*)&Wf[(f >> 6)*520 + (f & 63)*8] = *(const short8*)(src + f*8);
            }
        }
        __syncthreads();
        #pragma unroll
        for (int ks = 0; ks < 4; ++ks) {
            short8 a0 = *(const short8*)&Xf[((wave*2 + 0)*4 + ks)*520 + lane*8];
            short8 a1 = *(const short8*)&Xf[((wave*2 + 1)*4 + ks)*520 + lane*8];
            #pragma unroll
            for (int nt = 0; nt < 4; ++nt) {
                short8 bf = *(const short8*)&Wf[(ks*4 + quad)*520 + (nt*16 + l16)*8];
                acc[1][0][nt] = __builtin_amdgcn_mfma_f32_16x16x32_bf16(a0, bf, acc[1][0][nt], 0, 0, 0);
                acc[1][1][nt] = __builtin_amdgcn_mfma_f32_16x16x32_bf16(a1, bf, acc[1][1][nt], 0, 0, 0);
            }
        }
    }

    float wom = wscal[0] * (1.f/32.f);

    for (int hi = 0; hi < 2; ++hi) {
        int h = hp*2 + hi;
        __syncthreads();
        {
            float ss[2][4];
            float vv[2][4][4];
            #pragma unroll
            for (int mt = 0; mt < 2; ++mt)
                #pragma unroll
                for (int reg = 0; reg < 4; ++reg) ss[mt][reg] = 0.f;
            #pragma unroll
            for (int nt = 0; nt < 4; ++nt) {
                float bkv = bk[h*DK + nt*16 + l16];
                #pragma unroll
                for (int mt = 0; mt < 2; ++mt)
                    #pragma unroll
                    for (int reg = 0; reg < 4; ++reg) {
                        float v = acc[hi][mt][nt][reg] + bkv;
                        vv[mt][nt][reg] = v;
                        ss[mt][reg] += v*v;
                    }
            }
            #pragma unroll
            for (int d2 = 1; d2 <= 8; d2 <<= 1)
                #pragma unroll
                for (int mt = 0; mt < 2; ++mt)
                    #pragma unroll
                    for (int reg = 0; reg < 4; ++reg)
                        ss[mt][reg] += __shfl_xor(ss[mt][reg], d2);
            #pragma unroll
            for (int mt = 0; mt < 2; ++mt) {
                float inv[4];
                #pragma unroll
                for (int reg = 0; reg < 4; ++reg)
                    inv[reg] = 1.f / fmaxf(sqrtf(ss[mt][reg]), EPSN);
                #pragma unroll
                for (int nt = 0; nt < 4; ++nt)
                    #pragma unroll
                    for (int reg = 0; reg < 4; ++reg)
                        Kb[wave*32 + mt*16 + quad*4 + reg][nt*16 + l16] =
                            f2bf(vv[mt][nt][reg] * inv[reg]);
            }
        }
        __syncthreads();
        {
            f32x4 acc2[2][2];
            #pragma unroll
            for (int mt = 0; mt < 2; ++mt)
                #pragma unroll
                for (int nt = 0; nt < 2; ++nt) acc2[mt][nt] = (f32x4){0.f,0.f,0.f,0.f};
            #pragma unroll
            for (int ks = 0; ks < 2; ++ks) {
                short8 qa0 = *(const short8*)&Qs[l16     ][ks*32 + quad*8];
                short8 qa1 = *(const short8*)&Qs[16 + l16][ks*32 + quad*8];
                #pragma unroll
                for (int nt = 0; nt < 2; ++nt) {
                    short8 kf = *(const short8*)&Kb[wave*32 + nt*16 + l16][ks*32 + quad*8];
                    acc2[0][nt] = __builtin_amdgcn_mfma_f32_16x16x32_bf16(qa0, kf, acc2[0][nt], 0, 0, 0);
                    acc2[1][nt] = __builtin_amdgcn_mfma_f32_16x16x32_bf16(qa1, kf, acc2[1][nt], 0, 0, 0);
                }
            }
            #pragma unroll
            for (int mt = 0; mt < 2; ++mt)
                #pragma unroll
                for (int nt = 0; nt < 2; ++nt) {
                    int tcol = wave*32 + nt*16 + l16;
                    #pragma unroll
                    for (int reg = 0; reg < 4; ++reg) {
                        int m = mt*16 + quad*4 + reg;
                        int j = t0 + tcol - m;
                        if (j >= 0 && j < WN)
                            atomicAdd(&tnloc[tcol - m + 31], acc2[mt][nt][reg]);
                    }
                }
        }
        __syncthreads();
        if (tid < 159) {
            int j = t0 + tid - 31;
            if (j >= 0 && j < WN)
                atomicAdd(&logits[(size_t)(b*H + h)*WN + j], wom * tnloc[tid]);
            tnloc[tid] = 0.f;
        }
        if (hi == 0) {
            const float* qsrc = qhat + (size_t)(b*H + h + 1)*M*DK;
            int i = tid * 8;
            float4 a0 = *(const float4*)(qsrc + i);
            float4 a1 = *(const float4*)(qsrc + i + 4);
            S8U t8;
            t8.e[0]=f2bf(a0.x); t8.e[1]=f2bf(a0.y); t8.e[2]=f2bf(a0.z); t8.e[3]=f2bf(a0.w);
            t8.e[4]=f2bf(a1.x); t8.e[5]=f2bf(a1.y); t8.e[6]=f2bf(a1.z); t8.e[7]=f2bf(a1.w);
            *(short8*)&Qs[i >> 6][i & 63] = t8.v;
        }
    }
}

// ---------------------------------------------------------------------------
__global__ __launch_bounds__(1024) void softmax_k(float* __restrict__ logits,
                                                  float* __restrict__ alast)
{
    int bh = blockIdx.x;
    float* L = logits + (size_t)bh*WN;
    __shared__ float red[1024];
    int tid = threadIdx.x;
    float mx = -1e30f;
    for (int j = tid; j < WN; j += 1024) mx = fmaxf(mx, L[j]);
    red[tid] = mx; __syncthreads();
    for (int s2 = 512; s2 > 0; s2 >>= 1) {
        if (tid < s2) red[tid] = fmaxf(red[tid], red[tid+s2]);
        __syncthreads();
    }
    mx = red[0]; __syncthreads();
    float sm = 0.f;
    for (int j = tid; j < WN; j += 1024) sm += expf(L[j] - mx);
    red[tid] = sm; __syncthreads();
    for (int s2 = 512; s2 > 0; s2 >>= 1) {
        if (tid < s2) red[tid] += red[tid+s2];
        __syncthreads();
    }
    float inv = 1.f / red[0];
    for (int j = tid; j < WN; j += 1024) {
        float a = expf(L[j] - mx) * inv;
        L[j] = a;
        if (j == WN-1) alast[bh] = a;
    }
}

// ---------------------------------------------------------------------------
#define JC2 96
__global__ __launch_bounds__(256) void xbar_bf_k(
    const unsigned short* __restrict__ xbf, const float* __restrict__ attn,
    float* __restrict__ xbar)
{
    int chunk = blockIdx.x & 63;
    int b = blockIdx.x >> 6;
    int j0 = chunk * JC2;
    int lim = (WN-1) - j0; if (lim > JC2) lim = JC2; if (lim < 0) lim = 0;
    __shared__ float al[H][JC2];
    int tid = threadIdx.x;
    for (int i = tid; i < H*JC2; i += 256) {
        int hh = i / JC2, jj = i - hh*JC2;
        al[hh][jj] = (jj < lim) ? attn[(size_t)(b*H + hh)*WN + j0 + jj] : 0.f;
    }
    __syncthreads();
    int d0 = tid * 2;
    const unsigned* p = (const unsigned*)(xbf + ((size_t)b*S + 31 + j0)*DM + d0);
    float acc[H][2];
    #pragma unroll
    for (int hh = 0; hh < H; ++hh) { acc[hh][0] = 0.f; acc[hh][1] = 0.f; }
    #pragma unroll 4
    for (int jj = 0; jj < lim; ++jj) {
        unsigned u = p[(size_t)jj*(DM/2)];
        float x0 = bf2f((unsigned short)(u & 0xffff));
        float x1 = bf2f((unsigned short)(u >> 16));
        #pragma unroll
        for (int hh = 0; hh < H; ++hh) {
            float a = al[hh][jj];
            acc[hh][0] += a * x0;
            acc[hh][1] += a * x1;
        }
    }
    #pragma unroll
    for (int hh = 0; hh < H; ++hh) {
        atomicAdd(&xbar[(size_t)(b*H+hh)*DM + d0],     acc[hh][0]);
        atomicAdd(&xbar[(size_t)(b*H+hh)*DM + d0 + 1], acc[hh][1]);
    }
}

#define JC 191
__global__ __launch_bounds__(256) void xbar_k(
    const float* __restrict__ memory, const float* __restrict__ attn,
    float* __restrict__ xbar)
{
    int chunk = blockIdx.x & 31;
    int b = blockIdx.x >> 5;
    int j0 = chunk * JC;
    __shared__ float al[H][JC];
    int tid = threadIdx.x;
    for (int i = tid; i < H*JC; i += 256) {
        int hh = i / JC, jj = i - hh*JC;
        al[hh][jj] = attn[(size_t)(b*H + hh)*WN + j0 + jj];
    }
    __syncthreads();
    int d0 = tid * 2;
    float acc[H][2];
    #pragma unroll
    for (int hh = 0; hh < H; ++hh) { acc[hh][0] = 0.f; acc[hh][1] = 0.f; }
    for (int jj = 0; jj < JC; ++jj) {
        int t = 31 + j0 + jj;
        const float2 xv = *(const float2*)(memory + ((size_t)b*SM1 + t)*DM + d0);
        #pragma unroll
        for (int hh = 0; hh < H; ++hh) {
            float a = al[hh][jj];
            acc[hh][0] += a * xv.x;
            acc[hh][1] += a * xv.y;
        }
    }
    #pragma unroll
    for (int hh = 0; hh < H; ++hh) {
        atomicAdd(&xbar[(size_t)(b*H+hh)*DM + d0],     acc[hh][0]);
        atomicAdd(&xbar[(size_t)(b*H+hh)*DM + d0 + 1], acc[hh][1]);
    }
}

// ---------------------------------------------------------------------------
__global__ __launch_bounds__(512) void final_k(
    const float* __restrict__ x_pre, const float* __restrict__ xbar,
    const float* __restrict__ Wv, const float* __restrict__ bv,
    const float* __restrict__ WO, const float* __restrict__ bO,
    const float* __restrict__ alast, const float* __restrict__ res,
    const int* __restrict__ G, float* __restrict__ out)
{
    int b = blockIdx.x;
    int tid = threadIdx.x;
    __shared__ float gl[64*64];
    __shared__ float deta[512];
    for (int i = tid; i < 4096; i += 512) gl[i] = (float)G[(i & 63)*64 + (i >> 6)];
    __syncthreads();
    int h = tid >> 6, dk = tid & 63;
    float ala = alast[b*H + h];
    const float* xb  = xbar + (size_t)(b*H + h)*DM;
    const float* wvr = Wv + (size_t)tid*DM;
    const float* gcol = gl + dk;
    float s = 0.f;
    for (int e = 0; e < DM; e += 4) {
        float4 wv4 = *(const float4*)(wvr + e);
        float4 xb4 = *(const float4*)(xb + e);
        int eb = e & 63;
        s += wv4.x*gcol[eb*64]     *xb4.x + wv4.y*gcol[(eb+1)*64]*xb4.y
           + wv4.z*gcol[(eb+2)*64]*xb4.z + wv4.w*gcol[(eb+3)*64]*xb4.w;
    }
    float hist = s + bv[tid]*(1.f - ala);
    deta[tid] = hist + ala * res[b*DK + dk];
    __syncthreads();
    int dpos = tid;
    const float* wor = WO + (size_t)dpos*DM;
    const float* gcol2 = gl + (dpos & 63);
    float o = 0.f;
    for (int jj = 0; jj < DM; jj += 4) {
        float4 wo4 = *(const float4*)(wor + jj);
        int jb = jj & 63;
        o += wo4.x*gcol2[jb*64]     *deta[jj]   + wo4.y*gcol2[(jb+1)*64]*deta[jj+1]
           + wo4.z*gcol2[(jb+2)*64]*deta[jj+2] + wo4.w*gcol2[(jb+3)*64]*deta[jj+3];
    }
    out[(size_t)b*DM + dpos] = x_pre[(size_t)b*DM + dpos] + o + bO[dpos];
}

// ---------------------------------------------------------------------------
extern "C" void kernel_launch(void* const* d_in, const int* in_sizes, int n_in,
                              void* d_out, int out_size, void* d_ws, size_t ws_size,
                              hipStream_t stream)
{
    const float* memory = (const float*)d_in[0];
    const float* x_pre  = (const float*)d_in[1];
    const float* aux    = (const float*)d_in[2];
    const float* pos    = (const float*)d_in[3];
    const float* Wq  = (const float*)d_in[4];
    const float* bq  = (const float*)d_in[5];
    const float* Wk  = (const float*)d_in[6];
    const float* bk  = (const float*)d_in[7];
    const float* Wv  = (const float*)d_in[8];
    const float* bv  = (const float*)d_in[9];
    const float* Wqa = (const float*)d_in[10];
    const float* bqa = (const float*)d_in[11];
    const float* Wka = (const float*)d_in[12];
    const float* bka = (const float*)d_in[13];
    const float* Wqp = (const float*)d_in[14];
    const float* bqp = (const float*)d_in[15];
    const float* Wkp = (const float*)d_in[16];
    const float* bkp = (const float*)d_in[17];
    const float* W_ih = (const float*)d_in[18];
    const float* W_hh = (const float*)d_in[19];
    const float* b_ih = (const float*)d_in[20];
    const float* b_hh = (const float*)d_in[21];
    const float* WO  = (const float*)d_in[22];
    const float* bO  = (const float*)d_in[23];
    const float* w   = (const float*)d_in[24];
    const float* w_a = (const float*)d_in[25];
    const float* w_p = (const float*)d_in[26];
    const int*   G   = (const int*)d_in[27];
    (void)in_sizes; (void)n_in; (void)out_size;

    float* ws = (float*)d_ws;
    unsigned short* wkb  = (unsigned short*)(ws + WS_WKT);
    unsigned short* wkab = (unsigned short*)(ws + WS_WKAT);
    unsigned short* wkpb = (unsigned short*)(ws + WS_WKPT);
    float* qhat   = ws + WS_QHAT;
    float* qahat  = ws + WS_QAHAT;
    float* qphat  = ws + WS_QPHAT;
    float* logits = ws + WS_LOGITS;
    float* xbar   = ws + WS_XBAR;
    float* alast  = ws + WS_ALAST;
    float* resb   = ws + WS_RES;
    float* gi_all = ws + WS_GI;
    float* wqm    = ws + WS_WQM;
    unsigned short* xbf = (unsigned short*)(ws + WS_XBF);
    float* outp   = (float*)d_out;

    const size_t need = ((size_t)WS_XBF + 12582912) * 4;   // ~55.2 MB
    const bool big = (ws_size >= need);

    hipMemsetAsync(logits, 0, (size_t)(N_LOGITS + N_XBAR)*sizeof(float), stream);

    // prelude: prep_weights + gi + qaqp + (big: xcast) in one launch
    prelude_k<<<big ? (PREP_NB + GI_NB + QAQP_NB + XCAST_NB)
                    : (PREP_NB + GI_NB + QAQP_NB), 256, 0, stream>>>(
        Wk, Wka, Wkp, Wq, G, wkb, wkab, wkpb, wqm,
        memory, x_pre, W_ih, b_ih, gi_all, xbf,
        aux, pos, Wqa, bqa, Wqp, bqp, qahat, qphat);

    // qhat + gru (merged; gru tail hides under qhat's 1024 blocks)
    qhat_gru_k<<<1026, 256, 0, stream>>>(memory, x_pre, wqm, bq, qhat,
                                         gi_all, W_hh, b_hh, resb);

    if (big) {
        proj_fused_k<<<12288, 256, 0, stream>>>(
            xbf, wkb, bk, qhat, w,
            aux, wkab, bka, qahat, w_a,
            pos, wkpb, bkp, qphat, w_p, logits);
    } else {
        kproj_band_mfma2<<<48*BB*4, 256, 0, stream>>>(memory, x_pre, wkb, bk, qhat,
                                                      w, logits);
        ka_only_k<<<KA_NB, 256, 0, stream>>>(aux, wkab, bka, qahat, w_a, logits);
        kp_only_k<<<KA_NB, 256, 0, stream>>>(pos, wkpb, bkp, qphat, w_p, logits);
    }

    softmax_k<<<BB*H, 1024, 0, stream>>>(logits, alast);

    if (big)
        xbar_bf_k<<<BB*64, 256, 0, stream>>>(xbf, logits, xbar);
    else
        xbar_k<<<BB*32, 256, 0, stream>>>(memory, logits, xbar);

    final_k<<<BB, 512, 0, stream>>>(x_pre, xbar, Wv, bv, WO, bO, alast, resb, G, outp);
}

// Round 9
// 584.375 us; speedup vs baseline: 1.0388x; 1.0388x over previous
//
#include <hip/hip_runtime.h>
#include <math.h>

// ---- problem constants (fixed by setup_inputs) ----
#define BB   8
#define S    6144
#define SM1  6143          // memory rows; x[:,SM1,:] == x_pre
#define DM   512
#define H    8
#define DK   64
#define M    32
#define WN   6113          // k + T - M + 1
#define DA   256
#define DAh  32
#define DP   128
#define DPh  16
#define EPSN 1e-12f

// ---- workspace layout (float offsets) ----
#define WS_WKT    0                       // H*DM*DK bf16 packed Wk
#define WS_WKAT   262144                  // H*DA*DAh bf16 packed Wka
#define WS_WKPT   327680                  // H*DP*DPh bf16 packed Wkp
#define WS_QHAT   344064                  // B*H*M*DK fp32
#define WS_QAHAT  475136
#define WS_QPHAT  477184
#define WS_LOGITS 478208                  // B*H*WN
#define WS_XBAR   869440                  // B*H*DM
#define WS_ALAST  902208
#define WS_RES    902272
#define WS_GI     902784
#define WS_WQM    950400                  // H*DK*DM masked Wq fp32
#define WS_XBF    1212544                 // B*S*DM bf16 = 12582912 float-slots
#define N_LOGITS  391232
#define N_XBAR    32768

typedef __attribute__((ext_vector_type(8))) short short8;
typedef __attribute__((ext_vector_type(4))) float f32x4;

__device__ inline unsigned short f2bf(float f) {
    union { float f; unsigned u; } v; v.f = f;
    unsigned r = v.u + 0x7fffu + ((v.u >> 16) & 1u);   // RNE
    return (unsigned short)(r >> 16);
}
__device__ inline float bf2f(unsigned short u) {
    union { unsigned u; float f; } v; v.u = ((unsigned)u) << 16; return v.f;
}

union S8U { short8 v; unsigned short e[8]; };

// ===========================================================================
// prelude: prep_weights + gi + qaqp + xcast fused (all independent)
// ===========================================================================
#define PREP_NB  2368
#define GI_NB    248
#define QAQP_NB  64
#define XCAST_NB 12288

__global__ __launch_bounds__(256) void prelude_k(
    const float* __restrict__ Wk, const float* __restrict__ Wka,
    const float* __restrict__ Wkp, const float* __restrict__ Wq,
    const int* __restrict__ G,
    unsigned short* __restrict__ wkb, unsigned short* __restrict__ wkab,
    unsigned short* __restrict__ wkpb, float* __restrict__ wqm,
    const float* __restrict__ memory, const float* __restrict__ x_pre,
    const float* __restrict__ W_ih, const float* __restrict__ b_ih,
    float* __restrict__ gi_all, unsigned short* __restrict__ xbf,
    const float* __restrict__ aux, const float* __restrict__ pos,
    const float* __restrict__ Wqa, const float* __restrict__ bqa,
    const float* __restrict__ Wqp, const float* __restrict__ bqp,
    float* __restrict__ qahat, float* __restrict__ qphat)
{
    int bx = blockIdx.x, tid = threadIdx.x;
    __shared__ float pa[32][8];
    __shared__ float pp[16][16];

    if (bx < PREP_NB) {
        int idx = bx * 256 + tid;
        if (idx < H*DM*DK) {
            int k = idx & 63; int d = (idx >> 6) & 511; int h = idx >> 15;
            float v = Wk[(size_t)(h*DK + k)*DM + d] * (float)G[k*DK + (d & 63)];
            wkb[(size_t)h*DM*DK + (((d >> 3)*DK + k) << 3) + (d & 7)] = f2bf(v);
        }
        int i2 = idx - H*DM*DK;
        if (i2 >= 0 && i2 < H*DA*DAh) {
            int h = i2 >> 13; int r = i2 & 8191;
            int j = r & 7; int f = r >> 3;
            int c = f & 31; int a = (f >> 5)*8 + j;
            wkab[i2] = f2bf(Wka[(size_t)(h*DAh + c)*DA + a]);
        }
        int i3 = idx - H*DM*DK - H*DA*DAh;
        if (i3 >= 0 && i3 < H*DP*DPh) {
            int h = i3 >> 11; int r = i3 & 2047;
            int j = r & 7; int f = r >> 3;
            int c = f & 15; int p = (f >> 4)*8 + j;
            wkpb[i3] = f2bf(Wkp[(size_t)(h*DPh + c)*DP + p]);
        }
        int i4 = idx - H*DM*DK - H*DA*DAh - H*DP*DPh;
        if (i4 >= 0 && i4 < H*DK*DM) {
            int d = i4 & 511; int k = (i4 >> 9) & 63;
            wqm[i4] = Wq[i4] * (float)G[k*DK + (d & 63)];
        }
        return;
    }
    if (bx < PREP_NB + GI_NB) {
        if (tid < 192) {
            int gx = bx - PREP_NB;
            int t = gx >> 3, b = gx & 7, c = tid;
            const float* xr = memory + ((size_t)b*SM1 + (S - M) + t)*DM;
            const float* wr = W_ih + (size_t)c*DM;
            float s = b_ih[c];
            for (int d = 0; d < DM; d += 4) {
                float4 x4 = *(const float4*)(xr + d);
                float4 w4 = *(const float4*)(wr + d);
                s += x4.x*w4.x + x4.y*w4.y + x4.z*w4.z + x4.w*w4.w;
            }
            gi_all[((size_t)t*BB + b)*192 + c] = s;
        }
        return;
    }
    if (bx < PREP_NB + GI_NB + QAQP_NB) {
        int bh = bx - PREP_NB - GI_NB;
        int b = bh >> 3, h = bh & 7;
        {
            int c = tid & 31, ch = tid >> 5;
            const float* ar = aux + ((size_t)b*S + (S-1))*DA + ch*32;
            const float* wv = Wqa + (size_t)(h*DAh + c)*DA + ch*32;
            float s = 0.f;
            #pragma unroll
            for (int a = 0; a < 32; a += 4) {
                float4 a4 = *(const float4*)(ar + a);
                float4 w4 = *(const float4*)(wv + a);
                s += a4.x*w4.x + a4.y*w4.y + a4.z*w4.z + a4.w*w4.w;
            }
            pa[c][ch] = s;
        }
        {
            int c = tid & 15, ch = tid >> 4;
            const float* pr = pos + ((size_t)b*S + (S-1))*DP + ch*8;
            const float* wv = Wqp + (size_t)(h*DPh + c)*DP + ch*8;
            float4 a4 = *(const float4*)(pr);
            float4 w4 = *(const float4*)(wv);
            float4 a5 = *(const float4*)(pr + 4);
            float4 w5 = *(const float4*)(wv + 4);
            pp[c][ch] = a4.x*w4.x + a4.y*w4.y + a4.z*w4.z + a4.w*w4.w
                      + a5.x*w5.x + a5.y*w5.y + a5.z*w5.z + a5.w*w5.w;
        }
        __syncthreads();
        if (tid < 32) {
            float q = bqa[h*DAh + tid];
            #pragma unroll
            for (int ch = 0; ch < 8; ++ch) q += pa[tid][ch];
            float ss = q*q;
            #pragma unroll
            for (int d2 = 1; d2 <= 16; d2 <<= 1) ss += __shfl_xor(ss, d2);
            qahat[(size_t)bh*DAh + tid] = q / fmaxf(sqrtf(ss), EPSN);
        } else if (tid >= 64 && tid < 80) {
            int c = tid - 64;
            float q = bqp[h*DPh + c];
            #pragma unroll
            for (int ch = 0; ch < 16; ++ch) q += pp[c][ch];
            float ss = q*q;
            #pragma unroll
            for (int d2 = 1; d2 <= 8; d2 <<= 1) ss += __shfl_xor(ss, d2);
            qphat[(size_t)bh*DPh + c] = q / fmaxf(sqrtf(ss), EPSN);
        }
        return;
    }
    {   // xcast: x (memory ++ x_pre) fp32 -> bf16 row-major xbf[b][t][d]
        size_t e = ((size_t)(bx - PREP_NB - GI_NB - QAQP_NB)*256 + tid)*8;
        int b = (int)(e / ((size_t)S*DM));
        size_t r = e - (size_t)b*S*DM;
        int t = (int)(r >> 9);
        int d = (int)(r & 511);
        const float* src = (t < SM1) ? memory + ((size_t)b*SM1 + t)*DM + d
                                     : x_pre + (size_t)b*DM + d;
        float4 v0 = *(const float4*)src, v1 = *(const float4*)(src + 4);
        S8U t8;
        t8.e[0]=f2bf(v0.x); t8.e[1]=f2bf(v0.y); t8.e[2]=f2bf(v0.z); t8.e[3]=f2bf(v0.w);
        t8.e[4]=f2bf(v1.x); t8.e[5]=f2bf(v1.y); t8.e[6]=f2bf(v1.z); t8.e[7]=f2bf(v1.w);
        *(short8*)(xbf + e) = t8.v;
    }
}

// ===========================================================================
// qhat (1024 blocks) + gru_scan (2 blocks, 4 batches each) in one launch.
// ===========================================================================
__global__ __launch_bounds__(256) void qhat_gru_k(
    const float* __restrict__ memory, const float* __restrict__ x_pre,
    const float* __restrict__ wqm, const float* __restrict__ bq,
    float* __restrict__ qhat,
    const float* __restrict__ gi_all, const float* __restrict__ W_hh,
    const float* __restrict__ b_hh, float* __restrict__ res)
{
    int bx = blockIdx.x;
    int tid = threadIdx.x;
    __shared__ float part[2][4][64];

    if (bx < 1024) {
        int mp = bx & 15;
        int h  = (bx >> 4) & 7;
        int b  = bx >> 7;
        int k = tid & 63, dq = tid >> 6;

        int m0 = mp*2;
        int t0 = S - M + m0, t1 = t0 + 1;
        const float* x0 = ((t0 < SM1) ? memory + ((size_t)b*SM1 + t0)*DM
                                      : x_pre + (size_t)b*DM) + dq*128;
        const float* x1 = ((t1 < SM1) ? memory + ((size_t)b*SM1 + t1)*DM
                                      : x_pre + (size_t)b*DM) + dq*128;
        const float* wr = wqm + (size_t)(h*DK + k)*DM + dq*128;

        float s0 = 0.f, s1 = 0.f;
        #pragma unroll 8
        for (int d = 0; d < 128; d += 4) {
            float4 w4 = *(const float4*)(wr + d);
            float4 a4 = *(const float4*)(x0 + d);
            float4 b4 = *(const float4*)(x1 + d);
            s0 += w4.x*a4.x + w4.y*a4.y + w4.z*a4.z + w4.w*a4.w;
            s1 += w4.x*b4.x + w4.y*b4.y + w4.z*b4.z + w4.w*b4.w;
        }

        part[0][dq][k] = s0;
        part[1][dq][k] = s1;
        __syncthreads();

        if (tid < 128) {
            int mi = tid >> 6;
            int kk = tid & 63;
            float q = part[mi][0][kk] + part[mi][1][kk] + part[mi][2][kk] + part[mi][3][kk]
                    + bq[h*DK + kk];
            float ss = q*q;
            #pragma unroll
            for (int d2 = 1; d2 <= 32; d2 <<= 1) ss += __shfl_xor(ss, d2);
            qhat[((size_t)(b*H + h)*M + (m0 + mi))*DK + kk] = q / fmaxf(sqrtf(ss), EPSN);
        }
        return;
    }

    // ---- gru part: blocks 1024,1025; wave = one batch (b = bg*4 + wave)
    {
        int bg = bx - 1024;
        int b = bg*4 + (tid >> 6);
        int l = tid & 63;

        float w0[64], w1[64], w2[64];
        {
            const float* r0p = W_hh + (size_t)l*DK;
            const float* r1p = W_hh + (size_t)(64 + l)*DK;
            const float* r2p = W_hh + (size_t)(128 + l)*DK;
            #pragma unroll
            for (int i = 0; i < 16; ++i) {
                float4 a = *(const float4*)(r0p + i*4);
                w0[i*4]=a.x; w0[i*4+1]=a.y; w0[i*4+2]=a.z; w0[i*4+3]=a.w;
                float4 c = *(const float4*)(r1p + i*4);
                w1[i*4]=c.x; w1[i*4+1]=c.y; w1[i*4+2]=c.z; w1[i*4+3]=c.w;
                float4 e = *(const float4*)(r2p + i*4);
                w2[i*4]=e.x; w2[i*4+1]=e.y; w2[i*4+2]=e.z; w2[i*4+3]=e.w;
            }
        }
        float bh0 = b_hh[l], bh1 = b_hh[64 + l], bh2 = b_hh[128 + l];

        float h = 0.f;
        const float* g0 = gi_all + (size_t)b*192;
        float gr = g0[l], gz = g0[64 + l], gn = g0[128 + l];

        #pragma unroll 1
        for (int t = 0; t < 31; ++t) {
            float a0 = bh0, a1 = bh1, a2 = bh2;
            #pragma unroll
            for (int k = 0; k < 64; ++k) {
                float hk = __int_as_float(__builtin_amdgcn_readlane(__float_as_int(h), k));
                a0 += hk * w0[k];
                a1 += hk * w1[k];
                a2 += hk * w2[k];
            }
            float ngr = 0.f, ngz = 0.f, ngn = 0.f;
            if (t < 30) {
                const float* g2 = gi_all + ((size_t)(t+1)*BB + b)*192;
                ngr = g2[l]; ngz = g2[64 + l]; ngn = g2[128 + l];
            }
            float r = 1.f / (1.f + expf(-(gr + a0)));
            float z = 1.f / (1.f + expf(-(gz + a1)));
            float n = tanhf(gn + r * a2);
            h = (1.f - z)*n + z*h;
            gr = ngr; gz = ngz; gn = ngn;
        }
        res[b*DK + l] = h;
    }
}

// ===========================================================================
// proj bodies. Round-8 proved occupancy-invariance (210us at 34% AND 70%) ->
// the proj phase is L2/L3 TRAFFIC-bound: xbf (96MB) was re-read per head
// (8x = 768MB) + aux 4x + pos 4x ~= 1GB/dispatch. Fix: head-sharing.
//  - kproj: 2 heads/block, A-frag loaded once feeds both heads (768->384MB)
//  - ka/kp: 4 heads/block (192->96MB, 96->48MB)
// K-loop schedule/index structure stays v3-verbatim; per-head accumulation
// order unchanged -> bit-identical numerics.
// ===========================================================================
#define SMEM_BYTES 18816

// kproj 2-head: A direct from global once, B per head from packed wkb.
__device__ __forceinline__ void kproj2h_body(int bxx, int tid, unsigned char* smemraw,
    const unsigned short* __restrict__ xbf, const unsigned short* __restrict__ wkb,
    const float* __restrict__ bk, const float* __restrict__ qhat,
    const float* __restrict__ wscal, float* __restrict__ logits)
{
    int tile = bxx % 96, hp = (bxx / 96) & 3, b = bxx / 384;
    int h0 = hp*2;
    int t0 = tile * 64;
    int wave = tid >> 6, lane = tid & 63;
    int quad = lane >> 4, l16 = lane & 15;

    typedef unsigned short row72[72];
    row72* Qs = (row72*)smemraw;                       // 64 x 72 shorts = 9216 B (2 heads)
    row72* Kb = (row72*)(smemraw + 64*72*2);           // 64 x 72 shorts = 9216 B
    float* tnloc = (float*)(smemraw + 128*72*2);       // 95 floats

    {   // stage Qs bf16 for BOTH heads
        int i = tid * 8;
        #pragma unroll
        for (int hi = 0; hi < 2; ++hi) {
            const float* qsrc = qhat + (size_t)(b*H + h0 + hi)*M*DK;
            float4 a0 = *(const float4*)(qsrc + i);
            float4 a1 = *(const float4*)(qsrc + i + 4);
            S8U t8;
            t8.e[0]=f2bf(a0.x); t8.e[1]=f2bf(a0.y); t8.e[2]=f2bf(a0.z); t8.e[3]=f2bf(a0.w);
            t8.e[4]=f2bf(a1.x); t8.e[5]=f2bf(a1.y); t8.e[6]=f2bf(a1.z); t8.e[7]=f2bf(a1.w);
            *(short8*)&Qs[hi*32 + (i >> 6)][i & 63] = t8.v;
        }
    }
    if (tid < 95) tnloc[tid] = 0.f;

    f32x4 acc[2][4];
    #pragma unroll
    for (int hi = 0; hi < 2; ++hi)
        #pragma unroll
        for (int nt = 0; nt < 4; ++nt) acc[hi][nt] = (f32x4){0.f,0.f,0.f,0.f};

    const unsigned short* xrow = xbf + ((size_t)b*S + t0 + wave*16 + l16)*DM;
    const unsigned short* wh0 = wkb + (size_t)h0*DM*DK;
    const unsigned short* wh1 = wh0 + (size_t)DM*DK;

    #pragma unroll
    for (int ch = 0; ch < 4; ++ch) {
        #pragma unroll
        for (int ks = 0; ks < 4; ++ks) {
            short8 a = *(const short8*)(xrow + ch*128 + ks*32 + quad*8);
            size_t boff = (size_t)(((ch*16 + ks*4 + quad)*DK))*8;
            #pragma unroll
            for (int nt = 0; nt < 4; ++nt) {
                short8 bf0 = *(const short8*)(wh0 + boff + (nt*16 + l16)*8);
                short8 bf1 = *(const short8*)(wh1 + boff + (nt*16 + l16)*8);
                acc[0][nt] = __builtin_amdgcn_mfma_f32_16x16x32_bf16(a, bf0, acc[0][nt], 0, 0, 0);
                acc[1][nt] = __builtin_amdgcn_mfma_f32_16x16x32_bf16(a, bf1, acc[1][nt], 0, 0, 0);
            }
        }
    }

    float wom = wscal[0] * (1.f/32.f);

    #pragma unroll
    for (int hi = 0; hi < 2; ++hi) {
        int h = h0 + hi;
        __syncthreads();   // hi=0: Qs staged + tnloc zeroed; hi=1: prev QKT reads + writeout done
        {   // bias + row l2-norm + bf16 Kb
            float vv[4][4];
            float ss[4] = {0.f, 0.f, 0.f, 0.f};
            #pragma unroll
            for (int nt = 0; nt < 4; ++nt) {
                float bkv = bk[h*DK + nt*16 + l16];
                #pragma unroll
                for (int reg = 0; reg < 4; ++reg) {
                    float v = acc[hi][nt][reg] + bkv;
                    vv[nt][reg] = v;
                    ss[reg] += v*v;
                }
            }
            #pragma unroll
            for (int d2 = 1; d2 <= 8; d2 <<= 1)
                #pragma unroll
                for (int reg = 0; reg < 4; ++reg) ss[reg] += __shfl_xor(ss[reg], d2);
            #pragma unroll
            for (int reg = 0; reg < 4; ++reg) {
                float inv = 1.f / fmaxf(sqrtf(ss[reg]), EPSN);
                #pragma unroll
                for (int nt = 0; nt < 4; ++nt)
                    Kb[wave*16 + quad*4 + reg][nt*16 + l16] = f2bf(vv[nt][reg] * inv);
            }
        }
        __syncthreads();
        {   // banded Q.K^T: 32 m-rows x 64 t-cols; per-diagonal LDS scatter
            int mtile = wave & 1;
            int thalf = (wave >> 1) * 32;
            f32x4 acc2[2];
            acc2[0] = (f32x4){0.f,0.f,0.f,0.f};
            acc2[1] = (f32x4){0.f,0.f,0.f,0.f};
            #pragma unroll
            for (int ks = 0; ks < 2; ++ks) {
                short8 a = *(const short8*)&Qs[hi*32 + mtile*16 + l16][ks*32 + quad*8];
                #pragma unroll
                for (int nt = 0; nt < 2; ++nt) {
                    short8 kf = *(const short8*)&Kb[thalf + nt*16 + l16][ks*32 + quad*8];
                    acc2[nt] = __builtin_amdgcn_mfma_f32_16x16x32_bf16(a, kf, acc2[nt], 0, 0, 0);
                }
            }
            int m0 = mtile*16 + quad*4;
            #pragma unroll
            for (int nt = 0; nt < 2; ++nt) {
                int tl = thalf + nt*16 + l16;
                #pragma unroll
                for (int reg = 0; reg < 4; ++reg) {
                    int mm = m0 + reg;
                    int j = t0 + tl - mm;
                    if (j >= 0 && j < WN)
                        atomicAdd(&tnloc[tl - mm + 31], acc2[nt][reg]);
                }
            }
        }
        __syncthreads();
        if (tid < 95) {
            int j = t0 + tid - 31;
            if (j >= 0 && j < WN)
                atomicAdd(&logits[(size_t)(b*H + h)*WN + j], wom * tnloc[tid]);
            tnloc[tid] = 0.f;
        }
    }
}

// ka body: 4 heads per block, two-pass DA staging (LDS 16640 B). a-frag
// hoisted across heads; per-head k-order 0..7 unchanged.
__device__ __forceinline__ void ka_body(int g, int tid, unsigned char* smemraw,
    const float* __restrict__ aux, const unsigned short* __restrict__ wkab,
    const float* __restrict__ bka, const float* __restrict__ qahat,
    const float* __restrict__ wa, float* __restrict__ logits)
{
    int tile = g % 96;
    int hp   = (g / 96) & 1;
    int b    = g / 192;
    int j0   = tile * 64;
    int wave = tid >> 6, lane = tid & 63;
    int quad = lane >> 4, l16 = lane & 15;

    unsigned short* Xa = (unsigned short*)smemraw;     // 16*520 shorts = 16640 B

    int r = tid >> 2, seg = tid & 3;
    int jcl = j0 + r; if (jcl > WN-1) jcl = WN-1;
    int tt = r >> 4, lo = r & 15;
    const float* arb = aux + ((size_t)b*S + (31 + jcl))*DA;

    f32x4 acc[4][2];
    #pragma unroll
    for (int hi = 0; hi < 4; ++hi)
        #pragma unroll
        for (int nt = 0; nt < 2; ++nt) acc[hi][nt] = (f32x4){0.f,0.f,0.f,0.f};

    #pragma unroll
    for (int p = 0; p < 2; ++p) {
        if (p) __syncthreads();                // pass-0 compute done
        {   // stage d in [128p, 128p+128): thread covers 32 floats
            const float* ar = arb + p*128 + seg*32;
            #pragma unroll
            for (int gg = 0; gg < 4; ++gg) {
                float4 v0 = *(const float4*)(ar + gg*8);
                float4 v1 = *(const float4*)(ar + gg*8 + 4);
                S8U t8;
                t8.e[0]=f2bf(v0.x); t8.e[1]=f2bf(v0.y); t8.e[2]=f2bf(v0.z); t8.e[3]=f2bf(v0.w);
                t8.e[4]=f2bf(v1.x); t8.e[5]=f2bf(v1.y); t8.e[6]=f2bf(v1.z); t8.e[7]=f2bf(v1.w);
                *(short8*)&Xa[(tt*4 + seg)*520 + (gg*16 + lo)*8] = t8.v;
            }
        }
        __syncthreads();
        #pragma unroll
        for (int ks = 0; ks < 4; ++ks) {
            short8 a = *(const short8*)&Xa[(wave*4 + ks)*520 + lane*8];
            #pragma unroll
            for (int hi = 0; hi < 4; ++hi) {
                int h = hp*4 + hi;
                const unsigned short* wsrc = wkab + (size_t)h*DA*DAh;
                #pragma unroll
                for (int nt = 0; nt < 2; ++nt) {
                    short8 bf = *(const short8*)(wsrc +
                        (size_t)((((p*4 + ks)*4 + quad)*32) + nt*16 + l16)*8);
                    acc[hi][nt] = __builtin_amdgcn_mfma_f32_16x16x32_bf16(
                        a, bf, acc[hi][nt], 0, 0, 0);
                }
            }
        }
    }

    float wav = wa[0];
    #pragma unroll
    for (int hi = 0; hi < 4; ++hi) {
        int h = hp*4 + hi;
        float bk0 = bka[h*DAh + l16], bk1 = bka[h*DAh + 16 + l16];
        float q0 = qahat[(size_t)(b*H + h)*DAh + l16];
        float q1 = qahat[(size_t)(b*H + h)*DAh + 16 + l16];
        #pragma unroll
        for (int reg = 0; reg < 4; ++reg) {
            float v0 = acc[hi][0][reg] + bk0;
            float v1 = acc[hi][1][reg] + bk1;
            float ss = v0*v0 + v1*v1;
            float dp = v0*q0 + v1*q1;
            #pragma unroll
            for (int d2 = 1; d2 <= 8; d2 <<= 1) {
                ss += __shfl_xor(ss, d2);
                dp += __shfl_xor(dp, d2);
            }
            if (l16 == 0) {
                int j = j0 + wave*16 + quad*4 + reg;
                if (j < WN)
                    atomicAdd(&logits[(size_t)(b*H + h)*WN + j],
                              wav * dp / fmaxf(sqrtf(ss), EPSN));
            }
        }
    }
}

// kp body: 4 heads per block (LDS 16640 B), a-frag hoisted across heads.
__device__ __forceinline__ void kp_body(int g, int tid, unsigned char* smemraw,
    const float* __restrict__ pos, const unsigned short* __restrict__ wkpb,
    const float* __restrict__ bkp, const float* __restrict__ qphat,
    const float* __restrict__ wp, float* __restrict__ logits)
{
    int tile = g % 96;
    int hp   = (g / 96) & 1;
    int b    = g / 192;
    int j0   = tile * 64;
    int wave = tid >> 6, lane = tid & 63;
    int quad = lane >> 4, l16 = lane & 15;

    unsigned short* Xp = (unsigned short*)smemraw;     // 16*520 shorts

    {
        int r = tid >> 2, seg = tid & 3;
        int j = j0 + r; if (j > WN-1) j = WN-1;
        const float* pr = pos + ((size_t)b*S + (31 + j))*DP + seg*32;
        int tt = r >> 4, lo = r & 15;
        #pragma unroll
        for (int gg = 0; gg < 4; ++gg) {
            float4 v0 = *(const float4*)(pr + gg*8);
            float4 v1 = *(const float4*)(pr + gg*8 + 4);
            int d0 = seg*32 + gg*8;
            int ks = d0 >> 5, qd = (d0 >> 3) & 3;
            S8U t8;
            t8.e[0]=f2bf(v0.x); t8.e[1]=f2bf(v0.y); t8.e[2]=f2bf(v0.z); t8.e[3]=f2bf(v0.w);
            t8.e[4]=f2bf(v1.x); t8.e[5]=f2bf(v1.y); t8.e[6]=f2bf(v1.z); t8.e[7]=f2bf(v1.w);
            *(short8*)&Xp[(tt*4 + ks)*520 + (qd*16 + lo)*8] = t8.v;
        }
    }
    __syncthreads();

    f32x4 acc[4];
    #pragma unroll
    for (int hi = 0; hi < 4; ++hi) acc[hi] = (f32x4){0.f,0.f,0.f,0.f};

    #pragma unroll
    for (int ks = 0; ks < 4; ++ks) {
        short8 a = *(const short8*)&Xp[(wave*4 + ks)*520 + lane*8];
        #pragma unroll
        for (int hi = 0; hi < 4; ++hi) {
            int h = hp*4 + hi;
            const unsigned short* wsrc = wkpb + (size_t)h*DP*DPh;
            short8 bf = *(const short8*)(wsrc + (size_t)(((ks*4 + quad)*16) + l16)*8);
            acc[hi] = __builtin_amdgcn_mfma_f32_16x16x32_bf16(a, bf, acc[hi], 0, 0, 0);
        }
    }

    float wpv = wp[0];
    #pragma unroll
    for (int hi = 0; hi < 4; ++hi) {
        int h = hp*4 + hi;
        float bk0 = bkp[h*DPh + l16];
        float q0 = qphat[(size_t)(b*H + h)*DPh + l16];
        #pragma unroll
        for (int reg = 0; reg < 4; ++reg) {
            float v = acc[hi][reg] + bk0;
            float ss = v*v;
            float dp = v*q0;
            #pragma unroll
            for (int d2 = 1; d2 <= 8; d2 <<= 1) {
                ss += __shfl_xor(ss, d2);
                dp += __shfl_xor(dp, d2);
            }
            if (l16 == 0) {
                int j = j0 + wave*16 + quad*4 + reg;
                if (j < WN)
                    atomicAdd(&logits[(size_t)(b*H + h)*WN + j],
                              wpv * dp / fmaxf(sqrtf(ss), EPSN));
            }
        }
    }
}

// ---------------------------------------------------------------------------
// fused proj launch: kproj2h(3072) + ka4(1536) + kp4(1536), 2:1:1.
#define KA_NB 1536
__global__ __launch_bounds__(256, 4) void proj_fused_k(
    const unsigned short* __restrict__ xbf, const unsigned short* __restrict__ wkb,
    const float* __restrict__ bk, const float* __restrict__ qhat,
    const float* __restrict__ w,
    const float* __restrict__ aux, const unsigned short* __restrict__ wkab,
    const float* __restrict__ bka, const float* __restrict__ qahat,
    const float* __restrict__ wa,
    const float* __restrict__ pos, const unsigned short* __restrict__ wkpb,
    const float* __restrict__ bkp, const float* __restrict__ qphat,
    const float* __restrict__ wp,
    float* __restrict__ logits)
{
    __shared__ __align__(16) unsigned char smemraw[SMEM_BYTES];
    int bx = blockIdx.x;
    int g = bx >> 2, r = bx & 3;
    int tid = threadIdx.x;
    if (r < 2)
        kproj2h_body(g*2 + r, tid, smemraw, xbf, wkb, bk, qhat, w, logits);
    else if (r == 2)
        ka_body(g, tid, smemraw, aux, wkab, bka, qahat, wa, logits);
    else
        kp_body(g, tid, smemraw, pos, wkpb, bkp, qphat, wp, logits);
}

// small-path standalone wrappers
__global__ __launch_bounds__(256, 2) void ka_only_k(
    const float* __restrict__ aux, const unsigned short* __restrict__ wkab,
    const float* __restrict__ bka, const float* __restrict__ qahat,
    const float* __restrict__ wa, float* __restrict__ logits)
{
    __shared__ __align__(16) unsigned char smemraw[SMEM_BYTES];
    ka_body(blockIdx.x, threadIdx.x, smemraw, aux, wkab, bka, qahat, wa, logits);
}
__global__ __launch_bounds__(256, 2) void kp_only_k(
    const float* __restrict__ pos, const unsigned short* __restrict__ wkpb,
    const float* __restrict__ bkp, const float* __restrict__ qphat,
    const float* __restrict__ wp, float* __restrict__ logits)
{
    __shared__ __align__(16) unsigned char smemraw[SMEM_BYTES];
    kp_body(blockIdx.x, threadIdx.x, smemraw, pos, wkpb, bkp, qphat, wp, logits);
}

// ---------------------------------------------------------------------------
// OLD kproj (fallback when workspace too small for xbf)
__global__ __launch_bounds__(256, 2) void kproj_band_mfma2(
    const float* __restrict__ memory, const float* __restrict__ x_pre,
    const unsigned short* __restrict__ wkb, const float* __restrict__ bk,
    const float* __restrict__ qhat, const float* __restrict__ wscal,
    float* __restrict__ logits)
{
    int bx = blockIdx.x;
    int hp = bx & 3, b = (bx >> 2) & 7, tile = bx >> 5;
    int t0 = tile * 128;
    int tid = threadIdx.x;
    int wave = tid >> 6, lane = tid & 63;
    int quad = lane >> 4, l16 = lane & 15;

    __shared__ unsigned short Xf[32*520];
    __shared__ unsigned short Wf[16*520];
    __shared__ unsigned short Kb[128][72];
    __shared__ unsigned short Qs[M][72];
    __shared__ float tnloc[159];

    if (tid < 159) tnloc[tid] = 0.f;
    {
        int h = hp*2;
        const float* qsrc = qhat + (size_t)(b*H + h)*M*DK;
        int i = tid * 8;
        float4 a0 = *(const float4*)(qsrc + i);
        float4 a1 = *(const float4*)(qsrc + i + 4);
        S8U t8;
        t8.e[0]=f2bf(a0.x); t8.e[1]=f2bf(a0.y); t8.e[2]=f2bf(a0.z); t8.e[3]=f2bf(a0.w);
        t8.e[4]=f2bf(a1.x); t8.e[5]=f2bf(a1.y); t8.e[6]=f2bf(a1.z); t8.e[7]=f2bf(a1.w);
        *(short8*)&Qs[i >> 6][i & 63] = t8.v;
    }

    f32x4 acc[2][2][4];
    #pragma unroll
    for (int hi = 0; hi < 2; ++hi)
        #pragma unroll
        for (int mt = 0; mt < 2; ++mt)
            #pragma unroll
            for (int nt = 0; nt < 4; ++nt) acc[hi][mt][nt] = (f32x4){0.f,0.f,0.f,0.f};

    for (int ch = 0; ch < 4; ++ch) {
        __syncthreads();
        {
            int r = tid >> 1, half = tid & 1;
            int t = t0 + r;
            const float* xr = ((t < SM1) ? (memory + ((size_t)b*SM1 + t)*DM)
                                         : (x_pre + (size_t)b*DM)) + ch*128 + half*64;
            int tt = r >> 4, lo = r & 15;
            #pragma unroll
            for (int g = 0; g < 8; ++g) {
                float4 v0 = *(const float4*)(xr + g*8);
                float4 v1 = *(const float4*)(xr + g*8 + 4);
                int d0 = half*64 + g*8;
                int ks = d0 >> 5, qd = (d0 >> 3) & 3;
                S8U t8;
                t8.e[0]=f2bf(v0.x); t8.e[1]=f2bf(v0.y); t8.e[2]=f2bf(v0.z); t8.e[3]=f2bf(v0.w);
                t8.e[4]=f2bf(v1.x); t8.e[5]=f2bf(v1.y); t8.e[6]=f2bf(v1.z); t8.e[7]=f2bf(v1.w);
                *(short8*)&Xf[(tt*4 + ks)*520 + (qd*16 + lo)*8] = t8.v;
            }
        }
        {
            const unsigned short* src = wkb + (size_t)(hp*2)*DM*DK + (size_t)ch*8192;
            #pragma unroll
            for (int i = 0; i < 4; ++i) {
                int f = tid + 256*i;
                *(short8*)&Wf[(f >> 6)*520 + (f & 63)*8] = *(const short8*)(src + f*8);
            }
        }
        __syncthreads();
        #pragma unroll
        for (int ks = 0; ks < 4; ++ks) {
            short8 a0 = *(const short8*)&Xf[((wave*2 + 0)*4 + ks)*520 + lane*8];
            short8 a1 = *(const short8*)&Xf[((wave*2 + 1)*4 + ks)*520 + lane*8];
            #pragma unroll
            for (int nt = 0; nt < 4; ++nt) {
                short8 bf = *(const short8*)&Wf[(ks*4 + quad)*520 + (nt*16 + l16)*8];
                acc[0][0][nt] = __builtin_amdgcn_mfma_f32_16x16x32_bf16(a0, bf, acc[0][0][nt], 0, 0, 0);
                acc[0][1][nt] = __builtin_amdgcn_mfma_f32_16x16x32_bf16(a1, bf, acc[0][1][nt], 0, 0, 0);
            }
        }
        __syncthreads();
        {
            const unsigned short* src = wkb + (size_t)(hp*2 + 1)*DM*DK + (size_t)ch*8192;
            #pragma unroll
            for (int i = 0; i < 4; ++i) {
                int f = tid + 256*i;
                *(short8*)&Wf[(f >> 6)*520 + (f & 63)*8] = *(const short8*)(src + f*8);
            }
        }
        __syncthreads();
        #pragma unroll
        for (int ks = 0; ks < 4; ++ks) {
            short8 a0 = *(const short8*)&Xf[((wave*2 + 0)*4 + ks)*520 + lane*8];
            short8 a1 = *(const short8*)&Xf[((wave*2 + 1)*4 + ks)*520 + lane*8];
            #pragma unroll
            for (int nt = 0; nt < 4; ++nt) {
                short8 bf = *(const short8*)&Wf[(ks*4 + quad)*520 + (nt*16 + l16)*8];
                acc[1][0][nt] = __builtin_amdgcn_mfma_f32_16x16x32_bf16(a0, bf, acc[1][0][nt], 0, 0, 0);
                acc[1][1][nt] = __builtin_amdgcn_mfma_f32_16x16x32_bf16(a1, bf, acc[1][1][nt], 0, 0, 0);
            }
        }
    }

    float wom = wscal[0] * (1.f/32.f);

    for (int hi = 0; hi < 2; ++hi) {
        int h = hp*2 + hi;
        __syncthreads();
        {
            float ss[2][4];
            float vv[2][4][4];
            #pragma unroll
            for (int mt = 0; mt < 2; ++mt)
                #pragma unroll
                for (int reg = 0; reg < 4; ++reg) ss[mt][reg] = 0.f;
            #pragma unroll
            for (int nt = 0; nt < 4; ++nt) {
                float bkv = bk[h*DK + nt*16 + l16];
                #pragma unroll
                for (int mt = 0; mt < 2; ++mt)
                    #pragma unroll
                    for (int reg = 0; reg < 4; ++reg) {
                        float v = acc[hi][mt][nt][reg] + bkv;
                        vv[mt][nt][reg] = v;
                        ss[mt][reg] += v*v;
                    }
            }
            #pragma unroll
            for (int d2 = 1; d2 <= 8; d2 <<= 1)
                #pragma unroll
                for (int mt = 0; mt < 2; ++mt)
                    #pragma unroll
                    for (int reg = 0; reg < 4; ++reg)
                        ss[mt][reg] += __shfl_xor(ss[mt][reg], d2);
            #pragma unroll
            for (int mt = 0; mt < 2; ++mt) {
                float inv[4];
                #pragma unroll
                for (int reg = 0; reg < 4; ++reg)
                    inv[reg] = 1.f / fmaxf(sqrtf(ss[mt][reg]), EPSN);
                #pragma unroll
                for (int nt = 0; nt < 4; ++nt)
                    #pragma unroll
                    for (int reg = 0; reg < 4; ++reg)
                        Kb[wave*32 + mt*16 + quad*4 + reg][nt*16 + l16] =
                            f2bf(vv[mt][nt][reg] * inv[reg]);
            }
        }
        __syncthreads();
        {
            f32x4 acc2[2][2];
            #pragma unroll
            for (int mt = 0; mt < 2; ++mt)
                #pragma unroll
                for (int nt = 0; nt < 2; ++nt) acc2[mt][nt] = (f32x4){0.f,0.f,0.f,0.f};
            #pragma unroll
            for (int ks = 0; ks < 2; ++ks) {
                short8 qa0 = *(const short8*)&Qs[l16     ][ks*32 + quad*8];
                short8 qa1 = *(const short8*)&Qs[16 + l16][ks*32 + quad*8];
                #pragma unroll
                for (int nt = 0; nt < 2; ++nt) {
                    short8 kf = *(const short8*)&Kb[wave*32 + nt*16 + l16][ks*32 + quad*8];
                    acc2[0][nt] = __builtin_amdgcn_mfma_f32_16x16x32_bf16(qa0, kf, acc2[0][nt], 0, 0, 0);
                    acc2[1][nt] = __builtin_amdgcn_mfma_f32_16x16x32_bf16(qa1, kf, acc2[1][nt], 0, 0, 0);
                }
            }
            #pragma unroll
            for (int mt = 0; mt < 2; ++mt)
                #pragma unroll
                for (int nt = 0; nt < 2; ++nt) {
                    int tcol = wave*32 + nt*16 + l16;
                    #pragma unroll
                    for (int reg = 0; reg < 4; ++reg) {
                        int m = mt*16 + quad*4 + reg;
                        int j = t0 + tcol - m;
                        if (j >= 0 && j < WN)
                            atomicAdd(&tnloc[tcol - m + 31], acc2[mt][nt][reg]);
                    }
                }
        }
        __syncthreads();
        if (tid < 159) {
            int j = t0 + tid - 31;
            if (j >= 0 && j < WN)
                atomicAdd(&logits[(size_t)(b*H + h)*WN + j], wom * tnloc[tid]);
            tnloc[tid] = 0.f;
        }
        if (hi == 0) {
            const float* qsrc = qhat + (size_t)(b*H + h + 1)*M*DK;
            int i = tid * 8;
            float4 a0 = *(const float4*)(qsrc + i);
            float4 a1 = *(const float4*)(qsrc + i + 4);
            S8U t8;
            t8.e[0]=f2bf(a0.x); t8.e[1]=f2bf(a0.y); t8.e[2]=f2bf(a0.z); t8.e[3]=f2bf(a0.w);
            t8.e[4]=f2bf(a1.x); t8.e[5]=f2bf(a1.y); t8.e[6]=f2bf(a1.z); t8.e[7]=f2bf(a1.w);
            *(short8*)&Qs[i >> 6][i & 63] = t8.v;
        }
    }
}

// ---------------------------------------------------------------------------
__global__ __launch_bounds__(1024) void softmax_k(float* __restrict__ logits,
                                                  float* __restrict__ alast)
{
    int bh = blockIdx.x;
    float* L = logits + (size_t)bh*WN;
    __shared__ float red[1024];
    int tid = threadIdx.x;
    float mx = -1e30f;
    for (int j = tid; j < WN; j += 1024) mx = fmaxf(mx, L[j]);
    red[tid] = mx; __syncthreads();
    for (int s2 = 512; s2 > 0; s2 >>= 1) {
        if (tid < s2) red[tid] = fmaxf(red[tid], red[tid+s2]);
        __syncthreads();
    }
    mx = red[0]; __syncthreads();
    float sm = 0.f;
    for (int j = tid; j < WN; j += 1024) sm += expf(L[j] - mx);
    red[tid] = sm; __syncthreads();
    for (int s2 = 512; s2 > 0; s2 >>= 1) {
        if (tid < s2) red[tid] += red[tid+s2];
        __syncthreads();
    }
    float inv = 1.f / red[0];
    for (int j = tid; j < WN; j += 1024) {
        float a = expf(L[j] - mx) * inv;
        L[j] = a;
        if (j == WN-1) alast[bh] = a;
    }
}

// ---------------------------------------------------------------------------
#define JC2 96
__global__ __launch_bounds__(256) void xbar_bf_k(
    const unsigned short* __restrict__ xbf, const float* __restrict__ attn,
    float* __restrict__ xbar)
{
    int chunk = blockIdx.x & 63;
    int b = blockIdx.x >> 6;
    int j0 = chunk * JC2;
    int lim = (WN-1) - j0; if (lim > JC2) lim = JC2; if (lim < 0) lim = 0;
    __shared__ float al[H][JC2];
    int tid = threadIdx.x;
    for (int i = tid; i < H*JC2; i += 256) {
        int hh = i / JC2, jj = i - hh*JC2;
        al[hh][jj] = (jj < lim) ? attn[(size_t)(b*H + hh)*WN + j0 + jj] : 0.f;
    }
    __syncthreads();
    int d0 = tid * 2;
    const unsigned* p = (const unsigned*)(xbf + ((size_t)b*S + 31 + j0)*DM + d0);
    float acc[H][2];
    #pragma unroll
    for (int hh = 0; hh < H; ++hh) { acc[hh][0] = 0.f; acc[hh][1] = 0.f; }
    #pragma unroll 4
    for (int jj = 0; jj < lim; ++jj) {
        unsigned u = p[(size_t)jj*(DM/2)];
        float x0 = bf2f((unsigned short)(u & 0xffff));
        float x1 = bf2f((unsigned short)(u >> 16));
        #pragma unroll
        for (int hh = 0; hh < H; ++hh) {
            float a = al[hh][jj];
            acc[hh][0] += a * x0;
            acc[hh][1] += a * x1;
        }
    }
    #pragma unroll
    for (int hh = 0; hh < H; ++hh) {
        atomicAdd(&xbar[(size_t)(b*H+hh)*DM + d0],     acc[hh][0]);
        atomicAdd(&xbar[(size_t)(b*H+hh)*DM + d0 + 1], acc[hh][1]);
    }
}

#define JC 191
__global__ __launch_bounds__(256) void xbar_k(
    const float* __restrict__ memory, const float* __restrict__ attn,
    float* __restrict__ xbar)
{
    int chunk = blockIdx.x & 31;
    int b = blockIdx.x >> 5;
    int j0 = chunk * JC;
    __shared__ float al[H][JC];
    int tid = threadIdx.x;
    for (int i = tid; i < H*JC; i += 256) {
        int hh = i / JC, jj = i - hh*JC;
        al[hh][jj] = attn[(size_t)(b*H + hh)*WN + j0 + jj];
    }
    __syncthreads();
    int d0 = tid * 2;
    float acc[H][2];
    #pragma unroll
    for (int hh = 0; hh < H; ++hh) { acc[hh][0] = 0.f; acc[hh][1] = 0.f; }
    for (int jj = 0; jj < JC; ++jj) {
        int t = 31 + j0 + jj;
        const float2 xv = *(const float2*)(memory + ((size_t)b*SM1 + t)*DM + d0);
        #pragma unroll
        for (int hh = 0; hh < H; ++hh) {
            float a = al[hh][jj];
            acc[hh][0] += a * xv.x;
            acc[hh][1] += a * xv.y;
        }
    }
    #pragma unroll
    for (int hh = 0; hh < H; ++hh) {
        atomicAdd(&xbar[(size_t)(b*H+hh)*DM + d0],     acc[hh][0]);
        atomicAdd(&xbar[(size_t)(b*H+hh)*DM + d0 + 1], acc[hh][1]);
    }
}

// ---------------------------------------------------------------------------
__global__ __launch_bounds__(512) void final_k(
    const float* __restrict__ x_pre, const float* __restrict__ xbar,
    const float* __restrict__ Wv, const float* __restrict__ bv,
    const float* __restrict__ WO, const float* __restrict__ bO,
    const float* __restrict__ alast, const float* __restrict__ res,
    const int* __restrict__ G, float* __restrict__ out)
{
    int b = blockIdx.x;
    int tid = threadIdx.x;
    __shared__ float gl[64*64];
    __shared__ float deta[512];
    for (int i = tid; i < 4096; i += 512) gl[i] = (float)G[(i & 63)*64 + (i >> 6)];
    __syncthreads();
    int h = tid >> 6, dk = tid & 63;
    float ala = alast[b*H + h];
    const float* xb  = xbar + (size_t)(b*H + h)*DM;
    const float* wvr = Wv + (size_t)tid*DM;
    const float* gcol = gl + dk;
    float s = 0.f;
    for (int e = 0; e < DM; e += 4) {
        float4 wv4 = *(const float4*)(wvr + e);
        float4 xb4 = *(const float4*)(xb + e);
        int eb = e & 63;
        s += wv4.x*gcol[eb*64]     *xb4.x + wv4.y*gcol[(eb+1)*64]*xb4.y
           + wv4.z*gcol[(eb+2)*64]*xb4.z + wv4.w*gcol[(eb+3)*64]*xb4.w;
    }
    float hist = s + bv[tid]*(1.f - ala);
    deta[tid] = hist + ala * res[b*DK + dk];
    __syncthreads();
    int dpos = tid;
    const float* wor = WO + (size_t)dpos*DM;
    const float* gcol2 = gl + (dpos & 63);
    float o = 0.f;
    for (int jj = 0; jj < DM; jj += 4) {
        float4 wo4 = *(const float4*)(wor + jj);
        int jb = jj & 63;
        o += wo4.x*gcol2[jb*64]     *deta[jj]   + wo4.y*gcol2[(jb+1)*64]*deta[jj+1]
           + wo4.z*gcol2[(jb+2)*64]*deta[jj+2] + wo4.w*gcol2[(jb+3)*64]*deta[jj+3];
    }
    out[(size_t)b*DM + dpos] = x_pre[(size_t)b*DM + dpos] + o + bO[dpos];
}

// ---------------------------------------------------------------------------
extern "C" void kernel_launch(void* const* d_in, const int* in_sizes, int n_in,
                              void* d_out, int out_size, void* d_ws, size_t ws_size,
                              hipStream_t stream)
{
    const float* memory = (const float*)d_in[0];
    const float* x_pre  = (const float*)d_in[1];
    const float* aux    = (const float*)d_in[2];
    const float* pos    = (const float*)d_in[3];
    const float* Wq  = (const float*)d_in[4];
    const float* bq  = (const float*)d_in[5];
    const float* Wk  = (const float*)d_in[6];
    const float* bk  = (const float*)d_in[7];
    const float* Wv  = (const float*)d_in[8];
    const float* bv  = (const float*)d_in[9];
    const float* Wqa = (const float*)d_in[10];
    const float* bqa = (const float*)d_in[11];
    const float* Wka = (const float*)d_in[12];
    const float* bka = (const float*)d_in[13];
    const float* Wqp = (const float*)d_in[14];
    const float* bqp = (const float*)d_in[15];
    const float* Wkp = (const float*)d_in[16];
    const float* bkp = (const float*)d_in[17];
    const float* W_ih = (const float*)d_in[18];
    const float* W_hh = (const float*)d_in[19];
    const float* b_ih = (const float*)d_in[20];
    const float* b_hh = (const float*)d_in[21];
    const float* WO  = (const float*)d_in[22];
    const float* bO  = (const float*)d_in[23];
    const float* w   = (const float*)d_in[24];
    const float* w_a = (const float*)d_in[25];
    const float* w_p = (const float*)d_in[26];
    const int*   G   = (const int*)d_in[27];
    (void)in_sizes; (void)n_in; (void)out_size;

    float* ws = (float*)d_ws;
    unsigned short* wkb  = (unsigned short*)(ws + WS_WKT);
    unsigned short* wkab = (unsigned short*)(ws + WS_WKAT);
    unsigned short* wkpb = (unsigned short*)(ws + WS_WKPT);
    float* qhat   = ws + WS_QHAT;
    float* qahat  = ws + WS_QAHAT;
    float* qphat  = ws + WS_QPHAT;
    float* logits = ws + WS_LOGITS;
    float* xbar   = ws + WS_XBAR;
    float* alast  = ws + WS_ALAST;
    float* resb   = ws + WS_RES;
    float* gi_all = ws + WS_GI;
    float* wqm    = ws + WS_WQM;
    unsigned short* xbf = (unsigned short*)(ws + WS_XBF);
    float* outp   = (float*)d_out;

    const size_t need = ((size_t)WS_XBF + 12582912) * 4;   // ~55.2 MB
    const bool big = (ws_size >= need);

    hipMemsetAsync(logits, 0, (size_t)(N_LOGITS + N_XBAR)*sizeof(float), stream);

    // prelude: prep_weights + gi + qaqp + (big: xcast) in one launch
    prelude_k<<<big ? (PREP_NB + GI_NB + QAQP_NB + XCAST_NB)
                    : (PREP_NB + GI_NB + QAQP_NB), 256, 0, stream>>>(
        Wk, Wka, Wkp, Wq, G, wkb, wkab, wkpb, wqm,
        memory, x_pre, W_ih, b_ih, gi_all, xbf,
        aux, pos, Wqa, bqa, Wqp, bqp, qahat, qphat);

    // qhat + gru (merged; gru tail hides under qhat's 1024 blocks)
    qhat_gru_k<<<1026, 256, 0, stream>>>(memory, x_pre, wqm, bq, qhat,
                                         gi_all, W_hh, b_hh, resb);

    if (big) {
        proj_fused_k<<<6144, 256, 0, stream>>>(
            xbf, wkb, bk, qhat, w,
            aux, wkab, bka, qahat, w_a,
            pos, wkpb, bkp, qphat, w_p, logits);
    } else {
        kproj_band_mfma2<<<48*BB*4, 256, 0, stream>>>(memory, x_pre, wkb, bk, qhat,
                                                      w, logits);
        ka_only_k<<<KA_NB, 256, 0, stream>>>(aux, wkab, bka, qahat, w_a, logits);
        kp_only_k<<<KA_NB, 256, 0, stream>>>(pos, wkpb, bkp, qphat, w_p, logits);
    }

    softmax_k<<<BB*H, 1024, 0, stream>>>(logits, alast);

    if (big)
        xbar_bf_k<<<BB*64, 256, 0, stream>>>(xbf, logits, xbar);
    else
        xbar_k<<<BB*32, 256, 0, stream>>>(memory, logits, xbar);

    final_k<<<BB, 512, 0, stream>>>(x_pre, xbar, Wv, bv, WO, bO, alast, resb, G, outp);
}